// Round 1
// baseline (5255.142 us; speedup 1.0000x reference)
//
#include <hip/hip_runtime.h>

#define B_ 2
#define L_ 512
#define Q_ 512
#define E_ 1024
#define W_ 1024
#define D_ 8
#define H_ 32
#define NH_ 16
#define HD_ 64
#define SA_ 512
#define SO_ 1024
#define V_ 8192
#define T_ 6
#define SYNH_ 2048

#define BQ_ 1024  // B_*Q_
#define BL_ 1024  // B_*L_

typedef __attribute__((ext_vector_type(8))) short bf16x8;   // 8 bf16 = 4 VGPRs
typedef __attribute__((ext_vector_type(4))) float f32x4;    // MFMA 16x16 accum

__device__ __forceinline__ float gelu_f(float x) {
    const float c = 0.7978845608028654f; // sqrt(2/pi)
    float x3 = x * x * x;
    return 0.5f * x * (1.0f + tanhf(c * (x + 0.044715f * x3)));
}

// ---- bf16 helpers (RNE), no header-type dependence ----
__device__ __forceinline__ unsigned short f2bf(float x) {
    unsigned int u = __float_as_uint(x);
    u += 0x7fffu + ((u >> 16) & 1u);
    return (unsigned short)(u >> 16);
}
__device__ __forceinline__ float bf2f(unsigned short h) {
    return __uint_as_float(((unsigned int)h) << 16);
}

// ---- async global->LDS, 16B per lane (dest = wave-uniform base + lane*16) ----
__device__ __forceinline__ void gload16(const void* g, void* l) {
    __builtin_amdgcn_global_load_lds(
        (const __attribute__((address_space(1))) void*)g,
        (__attribute__((address_space(3))) void*)l, 16, 0, 0);
}

// =====================================================================
// Split-bf16 MFMA GEMM:  C = act(A@B + bias)
// A given as hi/lo bf16 planes, (M,K) row-major (K contiguous)
// B given as hi/lo bf16 planes, TRANSPOSED: (N,K) row-major (K contiguous)
// C fp32 (M,N) with arbitrary ldc. M%128==0, N%128==0, K%32==0.
// 256 threads = 4 waves in 2x2, each wave owns a 64x64 output quadrant
// (4x4 fragments of 16x16). Per K-step(32): 8 global_load_lds_dwordx4
// per thread-pair, 16 ds_read_b128 frags, 48 MFMA (hi*hi + hi*lo + lo*hi).
// =====================================================================
__global__ __launch_bounds__(256) void gemm_split(
    const unsigned short* __restrict__ Ah, const unsigned short* __restrict__ Al,
    const unsigned short* __restrict__ Bh, const unsigned short* __restrict__ Bl,
    float* __restrict__ C, int ldc, const float* __restrict__ bias,
    int M, int N, int K, int act)
{
    __shared__ unsigned short sAh[128 * 32];
    __shared__ unsigned short sAl[128 * 32];
    __shared__ unsigned short sBh[128 * 32];
    __shared__ unsigned short sBl[128 * 32];

    const int tid  = threadIdx.x;
    const int wave = tid >> 6;
    const int lane = tid & 63;
    const int bm = blockIdx.y * 128;
    const int bn = blockIdx.x * 128;
    const int wm = (wave >> 1) * 64;
    const int wn = (wave & 1) * 64;
    const int r15 = lane & 15;     // frag row/col within 16
    const int r4  = lane >> 4;     // k-group (0..3)

    f32x4 acc[4][4] = {};

    // staging: tile is 128 rows x 32 bf16 = 8192B = 512 chunks of 16B; 2 chunks/thread
    const int c0 = tid, c1 = tid + 256;
    const size_t aoff0 = (size_t)(bm + (c0 >> 2)) * K + (c0 & 3) * 8;
    const size_t aoff1 = (size_t)(bm + (c1 >> 2)) * K + (c1 & 3) * 8;
    const size_t boff0 = (size_t)(bn + (c0 >> 2)) * K + (c0 & 3) * 8;
    const size_t boff1 = (size_t)(bn + (c1 >> 2)) * K + (c1 & 3) * 8;
    const int l0 = wave * 512;          // shorts: chunk (wave*64)*8
    const int l1 = 2048 + wave * 512;   // shorts: chunk (256+wave*64)*8

    for (int k0 = 0; k0 < K; k0 += 32) {
        gload16(Ah + aoff0 + k0, sAh + l0);
        gload16(Ah + aoff1 + k0, sAh + l1);
        gload16(Al + aoff0 + k0, sAl + l0);
        gload16(Al + aoff1 + k0, sAl + l1);
        gload16(Bh + boff0 + k0, sBh + l0);
        gload16(Bh + boff1 + k0, sBh + l1);
        gload16(Bl + boff0 + k0, sBl + l0);
        gload16(Bl + boff1 + k0, sBl + l1);
        asm volatile("s_waitcnt vmcnt(0)" ::: "memory");
        __syncthreads();

        bf16x8 ahf[4], alf[4], bhf[4], blf[4];
#pragma unroll
        for (int i = 0; i < 4; ++i) {
            const int ra = (wm + i * 16 + r15) * 32 + r4 * 8;
            ahf[i] = *(const bf16x8*)(sAh + ra);
            alf[i] = *(const bf16x8*)(sAl + ra);
        }
#pragma unroll
        for (int j = 0; j < 4; ++j) {
            const int rb = (wn + j * 16 + r15) * 32 + r4 * 8;
            bhf[j] = *(const bf16x8*)(sBh + rb);
            blf[j] = *(const bf16x8*)(sBl + rb);
        }
#pragma unroll
        for (int i = 0; i < 4; ++i)
#pragma unroll
            for (int j = 0; j < 4; ++j) {
                acc[i][j] = __builtin_amdgcn_mfma_f32_16x16x32_bf16(ahf[i], bhf[j], acc[i][j], 0, 0, 0);
                acc[i][j] = __builtin_amdgcn_mfma_f32_16x16x32_bf16(ahf[i], blf[j], acc[i][j], 0, 0, 0);
                acc[i][j] = __builtin_amdgcn_mfma_f32_16x16x32_bf16(alf[i], bhf[j], acc[i][j], 0, 0, 0);
            }
        __syncthreads();
    }

    // epilogue: C/D layout col=lane&15, row=(lane>>4)*4+reg (m89-verified)
    const int crow0 = bm + wm + r4 * 4;
    const int ccol0 = bn + wn + r15;
#pragma unroll
    for (int i = 0; i < 4; ++i) {
#pragma unroll
        for (int j = 0; j < 4; ++j) {
            const int col = ccol0 + j * 16;
            const float bv = bias ? bias[col] : 0.0f;
#pragma unroll
            for (int r = 0; r < 4; ++r) {
                const int row = crow0 + i * 16 + r;
                float v = acc[i][j][r] + bv;
                if (act) v = gelu_f(v);
                C[(size_t)row * ldc + col] = v;
            }
        }
    }
}

// ---------------- fp32 -> split bf16 (row-major, no transpose) ----------------
__global__ void cvt_split(const float* __restrict__ X,
                          unsigned short* __restrict__ H, unsigned short* __restrict__ L,
                          size_t n4)
{
    size_t i = (size_t)blockIdx.x * 256 + threadIdx.x;
    if (i >= n4) return;
    float4 v = ((const float4*)X)[i];
    ushort4 h, l;
    h.x = f2bf(v.x); l.x = f2bf(v.x - bf2f(h.x));
    h.y = f2bf(v.y); l.y = f2bf(v.y - bf2f(h.y));
    h.z = f2bf(v.z); l.z = f2bf(v.z - bf2f(h.z));
    h.w = f2bf(v.w); l.w = f2bf(v.w - bf2f(h.w));
    ((ushort4*)H)[i] = h;
    ((ushort4*)L)[i] = l;
}

// ---------------- fp32 (R,C) -> split bf16 transposed (C,R) ----------------
__global__ __launch_bounds__(256) void cvt_split_T(
    const float* __restrict__ X, int R, int Cc,
    unsigned short* __restrict__ H, unsigned short* __restrict__ L)
{
    __shared__ float tile[32][33];
    const int rb = blockIdx.y * 32, cb = blockIdx.x * 32;
    const int tx = threadIdx.x & 31, ty = threadIdx.x >> 5;  // ty 0..7
#pragma unroll
    for (int r = 0; r < 32; r += 8)
        tile[ty + r][tx] = X[(size_t)(rb + ty + r) * Cc + cb + tx];
    __syncthreads();
#pragma unroll
    for (int r = 0; r < 32; r += 8) {
        float v = tile[tx][ty + r];
        unsigned short h = f2bf(v);
        unsigned short l = f2bf(v - bf2f(h));
        size_t o = (size_t)(cb + ty + r) * R + rb + tx;
        H[o] = h;
        L[o] = l;
    }
}

// ---------------- embedding gather ----------------
__global__ void gather_emb(const int* __restrict__ x, const float* __restrict__ emb,
                           float* __restrict__ out) {
    size_t i = (size_t)blockIdx.x * 256 + threadIdx.x;
    const int e4n = E_ / 4;
    size_t row = i / e4n;
    int e4 = (int)(i % e4n);
    const float4* src = (const float4*)(emb + (size_t)x[row] * E_) + e4;
    ((float4*)out)[i] = *src;
}

// ---------------- heads reshape (+ optional RoPE) ----------------
__global__ void rope_heads(const float* __restrict__ lin, float* __restrict__ out,
                           int S, int applyRope) {
    const int half = HD_ / 2;  // 32
    size_t idx = (size_t)blockIdx.x * 256 + threadIdx.x;
    size_t total = (size_t)B_ * S * NH_ * half;
    if (idx >= total) return;
    int d2 = (int)(idx % half);
    int h = (int)((idx / half) % NH_);
    int s = (int)((idx / ((size_t)half * NH_)) % S);
    int b = (int)(idx / ((size_t)half * NH_ * S));
    const float* src = lin + ((size_t)b * S + s) * E_ + h * HD_;
    float x1 = src[d2], x2 = src[d2 + half];
    float o1, o2;
    if (applyRope) {
        float invf = powf(10000.0f, -(float)d2 / (float)half);
        float ang = (float)s * invf;
        float c = cosf(ang), sn = sinf(ang);
        o1 = x1 * c - x2 * sn;
        o2 = x2 * c + x1 * sn;
    } else {
        o1 = x1; o2 = x2;
    }
    float* dst = out + (((size_t)b * NH_ + h) * S + s) * HD_;
    dst[d2] = o1;
    dst[d2 + half] = o2;
}

// ---------------- state init ----------------
__global__ void init_hist0(const float* __restrict__ z_init, float* __restrict__ hist0) {
    size_t i = (size_t)blockIdx.x * 256 + threadIdx.x;  // W*BQ
    if (i >= (size_t)W_ * BQ_) return;
    hist0[i] = z_init[i / BQ_];
}

__global__ void init_pah(const float* __restrict__ pah_init, float* __restrict__ pah) {
    size_t i = (size_t)blockIdx.x * 256 + threadIdx.x;  // W*BQ*D
    if (i >= (size_t)W_ * BQ_ * D_) return;
    int d = (int)(i % D_);
    int w = (int)(i / ((size_t)BQ_ * D_));
    pah[i] = pah_init[(size_t)w * D_ + d];
}

// ---------------- sync computation ----------------
__global__ __launch_bounds__(256) void sync_kernel(
    const float* __restrict__ hist, int Tn,
    const int* __restrict__ idx_l, const int* __restrict__ idx_r,
    const float* __restrict__ decay,
    float* __restrict__ out, int S) {
    const int s = blockIdx.y;
    const int bq = blockIdx.x * 256 + threadIdx.x;
    const int wl = idx_l[s], wr = idx_r[s];
    const float dc = decay[s];
    float num = 0.0f, den = 0.0f;
    for (int t = 0; t < Tn; ++t) {
        float wgt = expf(-(float)(Tn - 1 - t) * dc);
        const float* hp = hist + (size_t)t * W_ * BQ_;
        num = fmaf(wgt * hp[(size_t)wl * BQ_ + bq], hp[(size_t)wr * BQ_ + bq], num);
        den += wgt;
    }
    out[(size_t)bq * S + s] = num * rsqrtf(den);
}

// ---------------- attention (one block per (b,h,q)) ----------------
__global__ __launch_bounds__(128) void attn_kernel(
    const float* __restrict__ qh,  // (B,NH,Q,HD)
    const float* __restrict__ kh,  // (B,NH,L,HD)
    const float* __restrict__ vh,  // (B,NH,L,HD)
    float* __restrict__ ctx)       // (B,Q,E)
{
    int q = blockIdx.x, h = blockIdx.y, b = blockIdx.z;
    int tid = threadIdx.x;
    __shared__ float sQ[HD_];
    __shared__ float sS[L_];
    __shared__ float red[128];

    const float* qptr = qh + (((size_t)(b * NH_ + h)) * Q_ + q) * HD_;
    if (tid < HD_) sQ[tid] = qptr[tid];
    __syncthreads();

    const int kmax = q + (L_ - Q_);
    const float* kbase = kh + ((size_t)(b * NH_ + h)) * L_ * HD_;
    for (int k = tid; k < L_; k += 128) {
        float s;
        if (k <= kmax) {
            const float* kp = kbase + (size_t)k * HD_;
            float acc = 0.0f;
#pragma unroll
            for (int d = 0; d < HD_; ++d) acc = fmaf(sQ[d], kp[d], acc);
            s = acc * 0.125f;
        } else {
            s = -1e30f;
        }
        sS[k] = s;
    }
    __syncthreads();

    float m = -1e30f;
    for (int k = tid; k < L_; k += 128) m = fmaxf(m, sS[k]);
    red[tid] = m;
    __syncthreads();
    for (int s = 64; s > 0; s >>= 1) {
        if (tid < s) red[tid] = fmaxf(red[tid], red[tid + s]);
        __syncthreads();
    }
    m = red[0];
    __syncthreads();

    float sum = 0.0f;
    for (int k = tid; k < L_; k += 128) {
        float p = (k <= kmax) ? expf(sS[k] - m) : 0.0f;
        sS[k] = p;
        sum += p;
    }
    red[tid] = sum;
    __syncthreads();
    for (int s = 64; s > 0; s >>= 1) {
        if (tid < s) red[tid] += red[tid + s];
        __syncthreads();
    }
    float inv = 1.0f / red[0];
    __syncthreads();

    int d = tid & 63;
    int halfk = tid >> 6;
    const float* vbase = vh + ((size_t)(b * NH_ + h)) * L_ * HD_;
    float acc = 0.0f;
    int k0 = halfk * (L_ / 2), k1 = k0 + (L_ / 2);
    for (int k = k0; k < k1; ++k) acc = fmaf(sS[k], vbase[(size_t)k * HD_ + d], acc);
    red[tid] = acc;
    __syncthreads();
    if (tid < 64) {
        float o = (red[tid] + red[tid + 64]) * inv;
        ctx[((size_t)b * Q_ + q) * E_ + h * HD_ + d] = o;
    }
}

// ---------------- copy z into the concat buffer's second half ----------------
__global__ void copy_z_cat(const float* __restrict__ z, float* __restrict__ cat) {
    size_t i = (size_t)blockIdx.x * 256 + threadIdx.x;  // BQ*W
    if (i >= (size_t)BQ_ * W_) return;
    size_t bq = i / W_;
    int w = (int)(i % W_);
    cat[bq * (E_ + W_) + E_ + w] = z[(size_t)w * BQ_ + bq];
}

// ---------------- pah shift + NLM ----------------
__global__ __launch_bounds__(256) void nlm_kernel(
    float* __restrict__ pah,
    const float* __restrict__ pre,
    const float* __restrict__ w1,
    const float* __restrict__ b1,
    const float* __restrict__ w2,
    const float* __restrict__ b2,
    float* __restrict__ zout)
{
    const int w = blockIdx.y;
    const int bq = blockIdx.x * 256 + threadIdx.x;
    const int tid = threadIdx.x;

    __shared__ float w1s[D_ * H_];
    __shared__ float b1s[H_];
    __shared__ float w2s[H_];
    w1s[tid] = w1[(size_t)w * D_ * H_ + tid];
    if (tid < H_) {
        b1s[tid] = b1[(size_t)w * H_ + tid];
        w2s[tid] = w2[(size_t)w * H_ + tid];
    }
    __syncthreads();

    float* pp = pah + ((size_t)w * BQ_ + bq) * D_;
    float4 lo = *(float4*)pp;
    float4 hi = *(float4*)(pp + 4);
    float p[D_];
    p[0] = lo.y; p[1] = lo.z; p[2] = lo.w;
    p[3] = hi.x; p[4] = hi.y; p[5] = hi.z; p[6] = hi.w;
    p[7] = pre[(size_t)bq * W_ + w];
    *(float4*)pp = make_float4(p[0], p[1], p[2], p[3]);
    *(float4*)(pp + 4) = make_float4(p[4], p[5], p[6], p[7]);

    float zacc = b2[w];
#pragma unroll
    for (int j = 0; j < H_; ++j) {
        float a = b1s[j];
#pragma unroll
        for (int d = 0; d < D_; ++d) a = fmaf(p[d], w1s[d * H_ + j], a);
        zacc = fmaf(gelu_f(a), w2s[j], zacc);
    }
    zout[(size_t)w * BQ_ + bq] = zacc;
}

// ---------------- host orchestration ----------------
static inline void launch_gemm_split(const unsigned short* Ah, const unsigned short* Al,
                                     const unsigned short* Bth, const unsigned short* Btl,
                                     float* C, int ldc, const float* bias,
                                     int M, int N, int K, int act, hipStream_t s) {
    dim3 g(N / 128, M / 128);
    gemm_split<<<g, 256, 0, s>>>(Ah, Al, Bth, Btl, C, ldc, bias, M, N, K, act);
}

static inline void launch_cvt(const float* X, unsigned short* H, unsigned short* L,
                              size_t n, hipStream_t s) {
    size_t n4 = n / 4;
    cvt_split<<<(unsigned)((n4 + 255) / 256), 256, 0, s>>>(X, H, L, n4);
}

static inline void launch_cvtT(const float* X, int R, int C,
                               unsigned short* H, unsigned short* L, hipStream_t s) {
    dim3 g(C / 32, R / 32);
    cvt_split_T<<<g, 256, 0, s>>>(X, R, C, H, L);
}

extern "C" void kernel_launch(void* const* d_in, const int* in_sizes, int n_in,
                              void* d_out, int out_size, void* d_ws, size_t ws_size,
                              hipStream_t stream) {
    const int*   x        = (const int*)d_in[0];
    const float* emb      = (const float*)d_in[2];
    const float* w_kv     = (const float*)d_in[3];
    const float* w_q_sync = (const float*)d_in[4];
    const float* wq       = (const float*)d_in[5];
    const float* wk       = (const float*)d_in[6];
    const float* wv       = (const float*)d_in[7];
    const float* wo       = (const float*)d_in[8];
    const float* ws1      = (const float*)d_in[9];
    const float* bs1      = (const float*)d_in[10];
    const float* ws2      = (const float*)d_in[11];
    const float* bs2      = (const float*)d_in[12];
    const float* nlm_w1   = (const float*)d_in[13];
    const float* nlm_b1   = (const float*)d_in[14];
    const float* nlm_w2   = (const float*)d_in[15];
    const float* nlm_b2   = (const float*)d_in[16];
    const float* out_w    = (const float*)d_in[17];
    const float* out_b    = (const float*)d_in[18];
    const float* z_init   = (const float*)d_in[19];
    const float* pah_init = (const float*)d_in[20];
    const float* decay_a  = (const float*)d_in[21];
    const float* decay_o  = (const float*)d_in[22];
    const int*   idx_la   = (const int*)d_in[23];
    const int*   idx_ra   = (const int*)d_in[24];
    const int*   idx_lo   = (const int*)d_in[25];
    const int*   idx_ro   = (const int*)d_in[26];

    float* out = (float*)d_out;

    const size_t BQ  = BQ_;
    const size_t BL  = BL_;
    const size_t BQW = BQ * W_;
    const size_t M1  = (size_t)1024 * 1024;

    // ---- workspace carve ----
    float* p = (float*)d_ws;
    auto alloc = [&](size_t n) { float* r = p; p += n; return r; };
    auto alloc_us = [&](size_t n) { unsigned short* r = (unsigned short*)p; p += n / 2; return r; };

    float* emb_x  = alloc(M1);          // reused as h1 (spans emb_x+kv = 2M floats)
    float* kv     = alloc(M1);
    float* k_lin  = alloc(M1);          // reused as q2
    float* v_lin  = alloc(M1);          // reused as ctx
    float* kh     = alloc(M1);
    float* vh     = alloc(M1);
    float* qh     = alloc(M1);
    float* cat    = alloc(2 * M1);      // (BQ, E+W)
    float* pre    = alloc(M1);
    float* sync_a = alloc(BQ * SA_);
    float* sync_o = alloc(BQ * SO_);
    float* hist   = alloc((size_t)(T_ + 1) * BQW);
    float* pah    = alloc(BQW * D_);
    float* combined = alloc((size_t)SA_ * E_);  // w_q_sync @ wq, fp32

    float* h1  = emb_x;   // 2M floats, valid after one-time phase
    float* q2  = k_lin;
    float* ctx = v_lin;

    // split bf16 planes (ushort)
    unsigned short* embS_h = alloc_us(M1);            unsigned short* embS_l = alloc_us(M1);
    unsigned short* wkvT_h = alloc_us(M1);            unsigned short* wkvT_l = alloc_us(M1);
    unsigned short* kvS_h  = alloc_us(M1);            unsigned short* kvS_l  = alloc_us(M1);
    unsigned short* wkT_h  = alloc_us(M1);            unsigned short* wkT_l  = alloc_us(M1);
    unsigned short* wvT_h  = alloc_us(M1);            unsigned short* wvT_l  = alloc_us(M1);
    unsigned short* wqsS_h = alloc_us(M1 / 2);        unsigned short* wqsS_l = alloc_us(M1 / 2);
    unsigned short* wqT_h  = alloc_us(M1);            unsigned short* wqT_l  = alloc_us(M1);
    unsigned short* combT_h = alloc_us(M1 / 2);       unsigned short* combT_l = alloc_us(M1 / 2);
    unsigned short* woT_h  = alloc_us(M1);            unsigned short* woT_l  = alloc_us(M1);
    unsigned short* ws1T_h = alloc_us(4 * M1);        unsigned short* ws1T_l = alloc_us(4 * M1);
    unsigned short* ws2T_h = alloc_us(2 * M1);        unsigned short* ws2T_l = alloc_us(2 * M1);
    unsigned short* outwT_h = alloc_us(8 * M1);       unsigned short* outwT_l = alloc_us(8 * M1);
    unsigned short* saS_h  = alloc_us(M1 / 2);        unsigned short* saS_l  = alloc_us(M1 / 2);
    unsigned short* ctxS_h = alloc_us(M1);            unsigned short* ctxS_l = alloc_us(M1);
    unsigned short* catS_h = alloc_us(2 * M1);        unsigned short* catS_l = alloc_us(2 * M1);
    unsigned short* h1S_h  = alloc_us(2 * M1);        unsigned short* h1S_l  = alloc_us(2 * M1);
    unsigned short* soS_h  = alloc_us(M1);            unsigned short* soS_l  = alloc_us(M1);

    // ---- one-time precompute ----
    {
        size_t n = BL * (E_ / 4);
        gather_emb<<<(unsigned)((n + 255) / 256), 256, 0, stream>>>(x, emb, emb_x);
    }
    launch_cvt(emb_x, embS_h, embS_l, BL * E_, stream);
    launch_cvtT(w_kv, E_, E_, wkvT_h, wkvT_l, stream);
    launch_gemm_split(embS_h, embS_l, wkvT_h, wkvT_l, kv, E_, nullptr, (int)BL, E_, E_, 0, stream);
    launch_cvt(kv, kvS_h, kvS_l, BL * E_, stream);
    launch_cvtT(wk, E_, E_, wkT_h, wkT_l, stream);
    launch_cvtT(wv, E_, E_, wvT_h, wvT_l, stream);
    launch_gemm_split(kvS_h, kvS_l, wkT_h, wkT_l, kh /*tmp use k_lin? no, use kh later*/, E_, nullptr, (int)BL, E_, E_, 0, stream);
    // NOTE: wrote k-linear into kh temporarily; rope reads it below into its own buf.
    launch_gemm_split(kvS_h, kvS_l, wvT_h, wvT_l, vh /*tmp v-linear*/, E_, nullptr, (int)BL, E_, E_, 0, stream);
    {
        // rope from temp (kh holds k_lin, vh holds v_lin) into k_lin-named buffers:
        // reuse k_lin/v_lin as the final (B,NH,S,HD) head buffers.
        size_t n = (size_t)B_ * L_ * NH_ * (HD_ / 2);
        rope_heads<<<(unsigned)((n + 255) / 256), 256, 0, stream>>>(kh, k_lin, L_, 1);
        rope_heads<<<(unsigned)((n + 255) / 256), 256, 0, stream>>>(vh, v_lin, L_, 0);
    }
    // swap names: kh/vh now free; k_lin/v_lin hold the head tensors. Re-point:
    {
        float* tmp;
        tmp = kh; kh = k_lin; k_lin = tmp;   // kh -> head-K, k_lin -> scratch (q2 alias target)
        tmp = vh; vh = v_lin; v_lin = tmp;   // vh -> head-V, v_lin -> scratch (ctx alias target)
        q2  = k_lin;
        ctx = v_lin;
    }
    // fold wq: combined = w_q_sync @ wq  (SA,E)
    launch_cvt(w_q_sync, wqsS_h, wqsS_l, (size_t)SA_ * E_, stream);
    launch_cvtT(wq, E_, E_, wqT_h, wqT_l, stream);
    launch_gemm_split(wqsS_h, wqsS_l, wqT_h, wqT_l, combined, E_, nullptr, SA_, E_, E_, 0, stream);
    launch_cvtT(combined, SA_, E_, combT_h, combT_l, stream);
    // weight conversions
    launch_cvtT(wo, E_, E_, woT_h, woT_l, stream);
    launch_cvtT(ws1, E_ + W_, SYNH_, ws1T_h, ws1T_l, stream);
    launch_cvtT(ws2, SYNH_, W_, ws2T_h, ws2T_l, stream);
    launch_cvtT(out_w, SO_, V_, outwT_h, outwT_l, stream);

    init_hist0<<<(unsigned)((BQW + 255) / 256), 256, 0, stream>>>(z_init, hist);
    init_pah<<<(unsigned)((BQW * D_ + 255) / 256), 256, 0, stream>>>(pah_init, pah);
    {
        dim3 g(BQ_ / 256, SA_);
        sync_kernel<<<g, 256, 0, stream>>>(hist, 1, idx_la, idx_ra, decay_a, sync_a, SA_);
    }

    // ---- T iterations ----
    for (int t = 0; t < T_; ++t) {
        const float* z = hist + (size_t)t * BQW;

        launch_cvt(sync_a, saS_h, saS_l, BQ * SA_, stream);
        launch_gemm_split(saS_h, saS_l, combT_h, combT_l, q2, E_, nullptr, (int)BQ, E_, SA_, 0, stream);
        {
            size_t n = (size_t)B_ * Q_ * NH_ * (HD_ / 2);
            rope_heads<<<(unsigned)((n + 255) / 256), 256, 0, stream>>>(q2, qh, Q_, 1);
        }
        {
            dim3 g(Q_, NH_, B_);
            attn_kernel<<<g, 128, 0, stream>>>(qh, kh, vh, ctx);
        }
        launch_cvt(ctx, ctxS_h, ctxS_l, BQ * E_, stream);
        launch_gemm_split(ctxS_h, ctxS_l, woT_h, woT_l, cat, E_ + W_, nullptr, (int)BQ, E_, E_, 0, stream);
        copy_z_cat<<<(unsigned)((BQW + 255) / 256), 256, 0, stream>>>(z, cat);

        launch_cvt(cat, catS_h, catS_l, BQ * (E_ + W_), stream);
        launch_gemm_split(catS_h, catS_l, ws1T_h, ws1T_l, h1, SYNH_, bs1, (int)BQ, SYNH_, E_ + W_, 1, stream);
        launch_cvt(h1, h1S_h, h1S_l, BQ * SYNH_, stream);
        launch_gemm_split(h1S_h, h1S_l, ws2T_h, ws2T_l, pre, W_, bs2, (int)BQ, W_, SYNH_, 0, stream);

        float* znext = hist + (size_t)(t + 1) * BQW;
        {
            dim3 g(BQ_ / 256, W_);
            nlm_kernel<<<g, 256, 0, stream>>>(pah, pre, nlm_w1, nlm_b1, nlm_w2, nlm_b2, znext);
        }

        int Tn = t + 2;
        if (t < T_ - 1) {
            dim3 g(BQ_ / 256, SA_);
            sync_kernel<<<g, 256, 0, stream>>>(hist, Tn, idx_la, idx_ra, decay_a, sync_a, SA_);
        }
        {
            dim3 g(BQ_ / 256, SO_);
            sync_kernel<<<g, 256, 0, stream>>>(hist, Tn, idx_lo, idx_ro, decay_o, sync_o, SO_);
        }

        launch_cvt(sync_o, soS_h, soS_l, BQ * SO_, stream);
        float* out_t = out + (size_t)t * BQ * V_;
        launch_gemm_split(soS_h, soS_l, outwT_h, outwT_l, out_t, V_, out_b, (int)BQ, V_, SO_, 0, stream);
    }
}

// Round 2
// 2903.230 us; speedup vs baseline: 1.8101x; 1.8101x over previous
//
#include <hip/hip_runtime.h>

#define B_ 2
#define L_ 512
#define Q_ 512
#define E_ 1024
#define W_ 1024
#define D_ 8
#define H_ 32
#define NH_ 16
#define HD_ 64
#define SA_ 512
#define SO_ 1024
#define V_ 8192
#define T_ 6
#define SYNH_ 2048

#define BQ_ 1024  // B_*Q_
#define BL_ 1024  // B_*L_

typedef __attribute__((ext_vector_type(8))) short bf16x8;   // 8 bf16 = 4 VGPRs
typedef __attribute__((ext_vector_type(4))) float f32x4;    // MFMA 16x16 accum

__device__ __forceinline__ float gelu_f(float x) {
    const float c = 0.7978845608028654f; // sqrt(2/pi)
    float x3 = x * x * x;
    return 0.5f * x * (1.0f + tanhf(c * (x + 0.044715f * x3)));
}

// ---- bf16 helpers (RNE) ----
__device__ __forceinline__ unsigned short f2bf(float x) {
    unsigned int u = __float_as_uint(x);
    u += 0x7fffu + ((u >> 16) & 1u);
    return (unsigned short)(u >> 16);
}
__device__ __forceinline__ float bf2f(unsigned short h) {
    return __uint_as_float(((unsigned int)h) << 16);
}

// ---- async global->LDS, 16B per lane (dest = wave-uniform base + lane*16) ----
__device__ __forceinline__ void gload16(const void* g, void* l) {
    __builtin_amdgcn_global_load_lds(
        (const __attribute__((address_space(1))) void*)g,
        (__attribute__((address_space(3))) void*)l, 16, 0, 0);
}

// =====================================================================
// Split-bf16 MFMA GEMM:  C = act(A@B + bias)
// A: hi/lo bf16 planes, (M,K) row-major. B: hi/lo planes, TRANSPOSED (N,K).
// C fp32 (M,N), ldc arbitrary. M%128==0, N%128==0, K%32==0.
// =====================================================================
__global__ __launch_bounds__(256) void gemm_split(
    const unsigned short* __restrict__ Ah, const unsigned short* __restrict__ Al,
    const unsigned short* __restrict__ Bh, const unsigned short* __restrict__ Bl,
    float* __restrict__ C, int ldc, const float* __restrict__ bias,
    int M, int N, int K, int act)
{
    __shared__ unsigned short sAh[128 * 32];
    __shared__ unsigned short sAl[128 * 32];
    __shared__ unsigned short sBh[128 * 32];
    __shared__ unsigned short sBl[128 * 32];

    const int tid  = threadIdx.x;
    const int wave = tid >> 6;
    const int lane = tid & 63;
    const int bm = blockIdx.y * 128;
    const int bn = blockIdx.x * 128;
    const int wm = (wave >> 1) * 64;
    const int wn = (wave & 1) * 64;
    const int r15 = lane & 15;
    const int r4  = lane >> 4;

    f32x4 acc[4][4] = {};

    const int c0 = tid, c1 = tid + 256;
    const size_t aoff0 = (size_t)(bm + (c0 >> 2)) * K + (c0 & 3) * 8;
    const size_t aoff1 = (size_t)(bm + (c1 >> 2)) * K + (c1 & 3) * 8;
    const size_t boff0 = (size_t)(bn + (c0 >> 2)) * K + (c0 & 3) * 8;
    const size_t boff1 = (size_t)(bn + (c1 >> 2)) * K + (c1 & 3) * 8;
    const int l0 = wave * 512;
    const int l1 = 2048 + wave * 512;

    for (int k0 = 0; k0 < K; k0 += 32) {
        gload16(Ah + aoff0 + k0, sAh + l0);
        gload16(Ah + aoff1 + k0, sAh + l1);
        gload16(Al + aoff0 + k0, sAl + l0);
        gload16(Al + aoff1 + k0, sAl + l1);
        gload16(Bh + boff0 + k0, sBh + l0);
        gload16(Bh + boff1 + k0, sBh + l1);
        gload16(Bl + boff0 + k0, sBl + l0);
        gload16(Bl + boff1 + k0, sBl + l1);
        asm volatile("s_waitcnt vmcnt(0)" ::: "memory");
        __syncthreads();

        bf16x8 ahf[4], alf[4], bhf[4], blf[4];
#pragma unroll
        for (int i = 0; i < 4; ++i) {
            const int ra = (wm + i * 16 + r15) * 32 + r4 * 8;
            ahf[i] = *(const bf16x8*)(sAh + ra);
            alf[i] = *(const bf16x8*)(sAl + ra);
        }
#pragma unroll
        for (int j = 0; j < 4; ++j) {
            const int rb = (wn + j * 16 + r15) * 32 + r4 * 8;
            bhf[j] = *(const bf16x8*)(sBh + rb);
            blf[j] = *(const bf16x8*)(sBl + rb);
        }
#pragma unroll
        for (int i = 0; i < 4; ++i)
#pragma unroll
            for (int j = 0; j < 4; ++j) {
                acc[i][j] = __builtin_amdgcn_mfma_f32_16x16x32_bf16(ahf[i], bhf[j], acc[i][j], 0, 0, 0);
                acc[i][j] = __builtin_amdgcn_mfma_f32_16x16x32_bf16(ahf[i], blf[j], acc[i][j], 0, 0, 0);
                acc[i][j] = __builtin_amdgcn_mfma_f32_16x16x32_bf16(alf[i], bhf[j], acc[i][j], 0, 0, 0);
            }
        __syncthreads();
    }

    const int crow0 = bm + wm + r4 * 4;
    const int ccol0 = bn + wn + r15;
#pragma unroll
    for (int i = 0; i < 4; ++i) {
#pragma unroll
        for (int j = 0; j < 4; ++j) {
            const int col = ccol0 + j * 16;
            const float bv = bias ? bias[col] : 0.0f;
#pragma unroll
            for (int r = 0; r < 4; ++r) {
                const int row = crow0 + i * 16 + r;
                float v = acc[i][j][r] + bv;
                if (act) v = gelu_f(v);
                C[(size_t)row * ldc + col] = v;
            }
        }
    }
}

// =====================================================================
// MFMA flash attention (split-bf16, fp32 softmax).
// qhS: (B,NH,Q,HD) split planes; khS: (B,NH,L,HD) split; vtS: (B,NH,HD,L) split.
// Block: 256 thr = 4 waves; one (b,h,64-q-tile); wave owns 16 q-rows.
// Per 64-k-tile: stage K/V^T (swizzled src -> linear LDS), S = Q@K^T (3 mfma
// per frag), online softmax in-reg, split-P -> swizzled LDS, PV (3 mfma).
// =====================================================================
__global__ __launch_bounds__(256) void attn_mfma(
    const unsigned short* __restrict__ qh_h, const unsigned short* __restrict__ qh_l,
    const unsigned short* __restrict__ kh_h, const unsigned short* __restrict__ kh_l,
    const unsigned short* __restrict__ vt_h, const unsigned short* __restrict__ vt_l,
    float* __restrict__ ctx)
{
    __shared__ unsigned short sKh[64 * 64], sKl[64 * 64];
    __shared__ unsigned short sVh[64 * 64], sVl[64 * 64];
    __shared__ unsigned short sPh[64 * 64], sPl[64 * 64];

    const int tid  = threadIdx.x;
    const int wave = tid >> 6;
    const int lane = tid & 63;
    const int r15 = lane & 15;
    const int r4  = lane >> 4;
    const int qt = blockIdx.x;
    const int h  = blockIdx.y;
    const int b  = blockIdx.z;
    const int bh = b * NH_ + h;
    const int qbase = qt * 64 + wave * 16;

    // Q fragments straight from global: row = qbase+r15, d at ks*32 + r4*8
    bf16x8 qa[2][2];
    {
        const unsigned short* qr_h = qh_h + ((size_t)bh * Q_ + qbase + r15) * HD_ + r4 * 8;
        const unsigned short* qr_l = qh_l + ((size_t)bh * Q_ + qbase + r15) * HD_ + r4 * 8;
        qa[0][0] = *(const bf16x8*)(qr_h);
        qa[1][0] = *(const bf16x8*)(qr_h + 32);
        qa[0][1] = *(const bf16x8*)(qr_l);
        qa[1][1] = *(const bf16x8*)(qr_l + 32);
    }

    f32x4 of[4] = {};
    float mrow[4] = {-1e30f, -1e30f, -1e30f, -1e30f};
    float lrow[4] = {};

    // staging chunk math (8KB tile = 512x16B chunks; 2 per thread)
    const int row0 = tid >> 3,        i70 = tid & 7;          // chunks 0..255
    const int row1 = 32 + (tid >> 3), i71 = tid & 7;          // chunks 256..511
    // K tile: row-major (64 rows x 64 shorts), source pre-swizzled within row
    const int ko0 = row0 * 64 + ((i70 * 8) ^ ((row0 & 7) << 3));
    const int ko1 = row1 * 64 + ((i71 * 8) ^ ((row1 & 7) << 3));
    // V^T tile: rows are d (stride 512 in global), same within-row swizzle
    const size_t vo0 = (size_t)row0 * L_ + ((i70 * 8) ^ ((row0 & 7) << 3));
    const size_t vo1 = (size_t)row1 * L_ + ((i71 * 8) ^ ((row1 & 7) << 3));
    const int ld0 = wave * 512;          // shorts
    const int ld1 = 2048 + wave * 512;

    const unsigned short* kb_h = kh_h + (size_t)bh * L_ * HD_;
    const unsigned short* kb_l = kh_l + (size_t)bh * L_ * HD_;
    const unsigned short* vb_h = vt_h + (size_t)bh * HD_ * L_;
    const unsigned short* vb_l = vt_l + (size_t)bh * HD_ * L_;

    for (int kt = 0; kt <= qt; ++kt) {
        gload16(kb_h + kt * 4096 + ko0, sKh + ld0);
        gload16(kb_h + kt * 4096 + ko1, sKh + ld1);
        gload16(kb_l + kt * 4096 + ko0, sKl + ld0);
        gload16(kb_l + kt * 4096 + ko1, sKl + ld1);
        gload16(vb_h + vo0 + kt * 64, sVh + ld0);
        gload16(vb_h + vo1 + kt * 64, sVh + ld1);
        gload16(vb_l + vo0 + kt * 64, sVl + ld0);
        gload16(vb_l + vo1 + kt * 64, sVl + ld1);
        asm volatile("s_waitcnt vmcnt(0)" ::: "memory");
        __syncthreads();

        // ---- S = Q @ K^T (16 q-rows x 64 k-cols per wave) ----
        f32x4 sf[4] = {};
#pragma unroll
        for (int ks = 0; ks < 2; ++ks) {
#pragma unroll
            for (int j = 0; j < 4; ++j) {
                const int kr = j * 16 + r15;
                const int off = kr * 64 + (((ks * 32 + r4 * 8)) ^ ((kr & 7) << 3));
                bf16x8 kfh = *(const bf16x8*)(sKh + off);
                bf16x8 kfl = *(const bf16x8*)(sKl + off);
                sf[j] = __builtin_amdgcn_mfma_f32_16x16x32_bf16(qa[ks][0], kfh, sf[j], 0, 0, 0);
                sf[j] = __builtin_amdgcn_mfma_f32_16x16x32_bf16(qa[ks][0], kfl, sf[j], 0, 0, 0);
                sf[j] = __builtin_amdgcn_mfma_f32_16x16x32_bf16(qa[ks][1], kfh, sf[j], 0, 0, 0);
            }
        }

        // ---- scale + causal mask (diagonal tile only) ----
        const bool diag = (kt == qt);
#pragma unroll
        for (int j = 0; j < 4; ++j)
#pragma unroll
            for (int r = 0; r < 4; ++r) {
                float s = sf[j][r] * 0.125f;
                if (diag) {
                    int kg = kt * 64 + j * 16 + r15;
                    int qg = qt * 64 + wave * 16 + r4 * 4 + r;
                    if (kg > qg) s = -1e30f;
                }
                sf[j][r] = s;
            }

        // ---- online softmax (rows = r4*4 + r; reduce across 16-lane group) ----
        float pv[4][4];
#pragma unroll
        for (int r = 0; r < 4; ++r) {
            float mx = fmaxf(fmaxf(sf[0][r], sf[1][r]), fmaxf(sf[2][r], sf[3][r]));
#pragma unroll
            for (int d = 1; d < 16; d <<= 1) mx = fmaxf(mx, __shfl_xor(mx, d, 64));
            float mnew = fmaxf(mrow[r], mx);
            float corr = expf(mrow[r] - mnew);
            float rs = 0.0f;
#pragma unroll
            for (int j = 0; j < 4; ++j) {
                float pp = expf(sf[j][r] - mnew);
                pv[j][r] = pp;
                rs += pp;
            }
#pragma unroll
            for (int d = 1; d < 16; d <<= 1) rs += __shfl_xor(rs, d, 64);
            lrow[r] = lrow[r] * corr + rs;
            mrow[r] = mnew;
#pragma unroll
            for (int j = 0; j < 4; ++j) of[j][r] *= corr;
        }

        // ---- split P -> swizzled LDS ----
#pragma unroll
        for (int j = 0; j < 4; ++j)
#pragma unroll
            for (int r = 0; r < 4; ++r) {
                const int prow = wave * 16 + r4 * 4 + r;
                const int pcol = j * 16 + r15;
                const int off = prow * 64 + (pcol ^ ((prow & 7) << 3));
                unsigned short ph = f2bf(pv[j][r]);
                sPh[off] = ph;
                sPl[off] = f2bf(pv[j][r] - bf2f(ph));
            }
        __syncthreads();

        // ---- O += P @ V ----
#pragma unroll
        for (int ks = 0; ks < 2; ++ks) {
            const int arow = wave * 16 + r15;
            const int aoff = arow * 64 + (((ks * 32 + r4 * 8)) ^ ((arow & 7) << 3));
            bf16x8 pah = *(const bf16x8*)(sPh + aoff);
            bf16x8 pal = *(const bf16x8*)(sPl + aoff);
#pragma unroll
            for (int j = 0; j < 4; ++j) {
                const int vrow = j * 16 + r15;
                const int voff = vrow * 64 + (((ks * 32 + r4 * 8)) ^ ((vrow & 7) << 3));
                bf16x8 vfh = *(const bf16x8*)(sVh + voff);
                bf16x8 vfl = *(const bf16x8*)(sVl + voff);
                of[j] = __builtin_amdgcn_mfma_f32_16x16x32_bf16(pah, vfh, of[j], 0, 0, 0);
                of[j] = __builtin_amdgcn_mfma_f32_16x16x32_bf16(pah, vfl, of[j], 0, 0, 0);
                of[j] = __builtin_amdgcn_mfma_f32_16x16x32_bf16(pal, vfh, of[j], 0, 0, 0);
            }
        }
        __syncthreads();
    }

    // ---- epilogue: O / l -> ctx (B,Q,E) ----
    float linv[4];
#pragma unroll
    for (int r = 0; r < 4; ++r) linv[r] = 1.0f / lrow[r];
#pragma unroll
    for (int j = 0; j < 4; ++j)
#pragma unroll
        for (int r = 0; r < 4; ++r) {
            const int qg = qt * 64 + wave * 16 + r4 * 4 + r;
            const int dc = h * HD_ + j * 16 + r15;
            ctx[((size_t)b * Q_ + qg) * E_ + dc] = of[j][r] * linv[r];
        }
}

// ---------------- fp32 -> split bf16 (row-major) ----------------
__global__ void cvt_split(const float* __restrict__ X,
                          unsigned short* __restrict__ H, unsigned short* __restrict__ L,
                          size_t n4)
{
    size_t i = (size_t)blockIdx.x * 256 + threadIdx.x;
    if (i >= n4) return;
    float4 v = ((const float4*)X)[i];
    ushort4 h, l;
    h.x = f2bf(v.x); l.x = f2bf(v.x - bf2f(h.x));
    h.y = f2bf(v.y); l.y = f2bf(v.y - bf2f(h.y));
    h.z = f2bf(v.z); l.z = f2bf(v.z - bf2f(h.z));
    h.w = f2bf(v.w); l.w = f2bf(v.w - bf2f(h.w));
    ((ushort4*)H)[i] = h;
    ((ushort4*)L)[i] = l;
}

// ---------------- fp32 (R,C) -> split bf16 transposed (C,R) ----------------
__global__ __launch_bounds__(256) void cvt_split_T(
    const float* __restrict__ X, int R, int Cc,
    unsigned short* __restrict__ H, unsigned short* __restrict__ L)
{
    __shared__ float tile[32][33];
    const int rb = blockIdx.y * 32, cb = blockIdx.x * 32;
    const int tx = threadIdx.x & 31, ty = threadIdx.x >> 5;
#pragma unroll
    for (int r = 0; r < 32; r += 8)
        tile[ty + r][tx] = X[(size_t)(rb + ty + r) * Cc + cb + tx];
    __syncthreads();
#pragma unroll
    for (int r = 0; r < 32; r += 8) {
        float v = tile[tx][ty + r];
        unsigned short h = f2bf(v);
        unsigned short l = f2bf(v - bf2f(h));
        size_t o = (size_t)(cb + ty + r) * R + rb + tx;
        H[o] = h;
        L[o] = l;
    }
}

// ---- batched per-(b,h) transpose: (BH,L,HD) -> (BH,HD,L) split bf16 ----
__global__ __launch_bounds__(256) void cvt_split_T_bh(
    const float* __restrict__ X,
    unsigned short* __restrict__ H, unsigned short* __restrict__ L)
{
    __shared__ float tile[32][33];
    const int bh = blockIdx.z;
    const int rb = blockIdx.y * 32;   // L rows
    const int cb = blockIdx.x * 32;   // HD cols
    const int tx = threadIdx.x & 31, ty = threadIdx.x >> 5;
    const float* Xb = X + (size_t)bh * L_ * HD_;
#pragma unroll
    for (int r = 0; r < 32; r += 8)
        tile[ty + r][tx] = Xb[(size_t)(rb + ty + r) * HD_ + cb + tx];
    __syncthreads();
#pragma unroll
    for (int r = 0; r < 32; r += 8) {
        float v = tile[tx][ty + r];
        unsigned short h = f2bf(v);
        unsigned short l = f2bf(v - bf2f(h));
        size_t o = (size_t)bh * HD_ * L_ + (size_t)(cb + ty + r) * L_ + rb + tx;
        H[o] = h;
        L[o] = l;
    }
}

// ---------------- embedding gather ----------------
__global__ void gather_emb(const int* __restrict__ x, const float* __restrict__ emb,
                           float* __restrict__ out) {
    size_t i = (size_t)blockIdx.x * 256 + threadIdx.x;
    const int e4n = E_ / 4;
    size_t row = i / e4n;
    int e4 = (int)(i % e4n);
    const float4* src = (const float4*)(emb + (size_t)x[row] * E_) + e4;
    ((float4*)out)[i] = *src;
}

// ---------------- heads reshape (+ optional RoPE) ----------------
__global__ void rope_heads(const float* __restrict__ lin, float* __restrict__ out,
                           int S, int applyRope) {
    const int half = HD_ / 2;  // 32
    size_t idx = (size_t)blockIdx.x * 256 + threadIdx.x;
    size_t total = (size_t)B_ * S * NH_ * half;
    if (idx >= total) return;
    int d2 = (int)(idx % half);
    int h = (int)((idx / half) % NH_);
    int s = (int)((idx / ((size_t)half * NH_)) % S);
    int b = (int)(idx / ((size_t)half * NH_ * S));
    const float* src = lin + ((size_t)b * S + s) * E_ + h * HD_;
    float x1 = src[d2], x2 = src[d2 + half];
    float o1, o2;
    if (applyRope) {
        float invf = powf(10000.0f, -(float)d2 / (float)half);
        float ang = (float)s * invf;
        float c = cosf(ang), sn = sinf(ang);
        o1 = x1 * c - x2 * sn;
        o2 = x2 * c + x1 * sn;
    } else {
        o1 = x1; o2 = x2;
    }
    float* dst = out + (((size_t)b * NH_ + h) * S + s) * HD_;
    dst[d2] = o1;
    dst[d2 + half] = o2;
}

// ---------------- state init ----------------
__global__ void init_hist0(const float* __restrict__ z_init, float* __restrict__ hist0) {
    size_t i = (size_t)blockIdx.x * 256 + threadIdx.x;  // W*BQ
    if (i >= (size_t)W_ * BQ_) return;
    hist0[i] = z_init[i / BQ_];
}

__global__ void init_pah(const float* __restrict__ pah_init, float* __restrict__ pah) {
    size_t i = (size_t)blockIdx.x * 256 + threadIdx.x;  // W*BQ*D
    if (i >= (size_t)W_ * BQ_ * D_) return;
    int d = (int)(i % D_);
    int w = (int)(i / ((size_t)BQ_ * D_));
    pah[i] = pah_init[(size_t)w * D_ + d];
}

// ---------------- sync computation ----------------
__global__ __launch_bounds__(256) void sync_kernel(
    const float* __restrict__ hist, int Tn,
    const int* __restrict__ idx_l, const int* __restrict__ idx_r,
    const float* __restrict__ decay,
    float* __restrict__ out, int S) {
    const int s = blockIdx.y;
    const int bq = blockIdx.x * 256 + threadIdx.x;
    const int wl = idx_l[s], wr = idx_r[s];
    const float dc = decay[s];
    float num = 0.0f, den = 0.0f;
    for (int t = 0; t < Tn; ++t) {
        float wgt = expf(-(float)(Tn - 1 - t) * dc);
        const float* hp = hist + (size_t)t * W_ * BQ_;
        num = fmaf(wgt * hp[(size_t)wl * BQ_ + bq], hp[(size_t)wr * BQ_ + bq], num);
        den += wgt;
    }
    out[(size_t)bq * S + s] = num * rsqrtf(den);
}

// ---------------- copy z into the concat buffer's second half ----------------
__global__ void copy_z_cat(const float* __restrict__ z, float* __restrict__ cat) {
    size_t i = (size_t)blockIdx.x * 256 + threadIdx.x;  // BQ*W
    if (i >= (size_t)BQ_ * W_) return;
    size_t bq = i / W_;
    int w = (int)(i % W_);
    cat[bq * (E_ + W_) + E_ + w] = z[(size_t)w * BQ_ + bq];
}

// ---------------- pah shift + NLM ----------------
__global__ __launch_bounds__(256) void nlm_kernel(
    float* __restrict__ pah,
    const float* __restrict__ pre,
    const float* __restrict__ w1,
    const float* __restrict__ b1,
    const float* __restrict__ w2,
    const float* __restrict__ b2,
    float* __restrict__ zout)
{
    const int w = blockIdx.y;
    const int bq = blockIdx.x * 256 + threadIdx.x;
    const int tid = threadIdx.x;

    __shared__ float w1s[D_ * H_];
    __shared__ float b1s[H_];
    __shared__ float w2s[H_];
    w1s[tid] = w1[(size_t)w * D_ * H_ + tid];
    if (tid < H_) {
        b1s[tid] = b1[(size_t)w * H_ + tid];
        w2s[tid] = w2[(size_t)w * H_ + tid];
    }
    __syncthreads();

    float* pp = pah + ((size_t)w * BQ_ + bq) * D_;
    float4 lo = *(float4*)pp;
    float4 hi = *(float4*)(pp + 4);
    float p[D_];
    p[0] = lo.y; p[1] = lo.z; p[2] = lo.w;
    p[3] = hi.x; p[4] = hi.y; p[5] = hi.z; p[6] = hi.w;
    p[7] = pre[(size_t)bq * W_ + w];
    *(float4*)pp = make_float4(p[0], p[1], p[2], p[3]);
    *(float4*)(pp + 4) = make_float4(p[4], p[5], p[6], p[7]);

    float zacc = b2[w];
#pragma unroll
    for (int j = 0; j < H_; ++j) {
        float a = b1s[j];
#pragma unroll
        for (int d = 0; d < D_; ++d) a = fmaf(p[d], w1s[d * H_ + j], a);
        zacc = fmaf(gelu_f(a), w2s[j], zacc);
    }
    zout[(size_t)w * BQ_ + bq] = zacc;
}

// ---------------- host orchestration ----------------
static inline void launch_gemm_split(const unsigned short* Ah, const unsigned short* Al,
                                     const unsigned short* Bth, const unsigned short* Btl,
                                     float* C, int ldc, const float* bias,
                                     int M, int N, int K, int act, hipStream_t s) {
    dim3 g(N / 128, M / 128);
    gemm_split<<<g, 256, 0, s>>>(Ah, Al, Bth, Btl, C, ldc, bias, M, N, K, act);
}

static inline void launch_cvt(const float* X, unsigned short* H, unsigned short* L,
                              size_t n, hipStream_t s) {
    size_t n4 = n / 4;
    cvt_split<<<(unsigned)((n4 + 255) / 256), 256, 0, s>>>(X, H, L, n4);
}

static inline void launch_cvtT(const float* X, int R, int C,
                               unsigned short* H, unsigned short* L, hipStream_t s) {
    dim3 g(C / 32, R / 32);
    cvt_split_T<<<g, 256, 0, s>>>(X, R, C, H, L);
}

extern "C" void kernel_launch(void* const* d_in, const int* in_sizes, int n_in,
                              void* d_out, int out_size, void* d_ws, size_t ws_size,
                              hipStream_t stream) {
    const int*   x        = (const int*)d_in[0];
    const float* emb      = (const float*)d_in[2];
    const float* w_kv     = (const float*)d_in[3];
    const float* w_q_sync = (const float*)d_in[4];
    const float* wq       = (const float*)d_in[5];
    const float* wk       = (const float*)d_in[6];
    const float* wv       = (const float*)d_in[7];
    const float* wo       = (const float*)d_in[8];
    const float* ws1      = (const float*)d_in[9];
    const float* bs1      = (const float*)d_in[10];
    const float* ws2      = (const float*)d_in[11];
    const float* bs2      = (const float*)d_in[12];
    const float* nlm_w1   = (const float*)d_in[13];
    const float* nlm_b1   = (const float*)d_in[14];
    const float* nlm_w2   = (const float*)d_in[15];
    const float* nlm_b2   = (const float*)d_in[16];
    const float* out_w    = (const float*)d_in[17];
    const float* out_b    = (const float*)d_in[18];
    const float* z_init   = (const float*)d_in[19];
    const float* pah_init = (const float*)d_in[20];
    const float* decay_a  = (const float*)d_in[21];
    const float* decay_o  = (const float*)d_in[22];
    const int*   idx_la   = (const int*)d_in[23];
    const int*   idx_ra   = (const int*)d_in[24];
    const int*   idx_lo   = (const int*)d_in[25];
    const int*   idx_ro   = (const int*)d_in[26];

    float* out = (float*)d_out;

    const size_t BQ  = BQ_;
    const size_t BL  = BL_;
    const size_t BQW = BQ * W_;
    const size_t M1  = (size_t)1024 * 1024;

    // ---- workspace carve ----
    float* p = (float*)d_ws;
    auto alloc = [&](size_t n) { float* r = p; p += n; return r; };
    auto alloc_us = [&](size_t n) { unsigned short* r = (unsigned short*)p; p += n / 2; return r; };

    float* emb_x  = alloc(M1);          // reused as h1 (spans emb_x+kv = 2M floats)
    float* kv     = alloc(M1);
    float* k_lin  = alloc(M1);          // reused as q2
    float* v_lin  = alloc(M1);          // reused as ctx
    float* kh     = alloc(M1);
    float* vh     = alloc(M1);
    float* qh     = alloc(M1);
    float* cat    = alloc(2 * M1);      // (BQ, E+W)
    float* pre    = alloc(M1);
    float* sync_a = alloc(BQ * SA_);
    float* sync_o = alloc(BQ * SO_);
    float* hist   = alloc((size_t)(T_ + 1) * BQW);
    float* pah    = alloc(BQW * D_);
    float* combined = alloc((size_t)SA_ * E_);  // w_q_sync @ wq, fp32

    float* h1  = emb_x;   // 2M floats, valid after one-time phase
    float* q2  = k_lin;
    float* ctx = v_lin;

    // split bf16 planes (ushort)
    unsigned short* embS_h = alloc_us(M1);            unsigned short* embS_l = alloc_us(M1);
    unsigned short* wkvT_h = alloc_us(M1);            unsigned short* wkvT_l = alloc_us(M1);
    unsigned short* kvS_h  = alloc_us(M1);            unsigned short* kvS_l  = alloc_us(M1);
    unsigned short* wkT_h  = alloc_us(M1);            unsigned short* wkT_l  = alloc_us(M1);
    unsigned short* wvT_h  = alloc_us(M1);            unsigned short* wvT_l  = alloc_us(M1);
    unsigned short* wqsS_h = alloc_us(M1 / 2);        unsigned short* wqsS_l = alloc_us(M1 / 2);
    unsigned short* wqT_h  = alloc_us(M1);            unsigned short* wqT_l  = alloc_us(M1);
    unsigned short* combT_h = alloc_us(M1 / 2);       unsigned short* combT_l = alloc_us(M1 / 2);
    unsigned short* woT_h  = alloc_us(M1);            unsigned short* woT_l  = alloc_us(M1);
    unsigned short* ws1T_h = alloc_us(4 * M1);        unsigned short* ws1T_l = alloc_us(4 * M1);
    unsigned short* ws2T_h = alloc_us(2 * M1);        unsigned short* ws2T_l = alloc_us(2 * M1);
    unsigned short* outwT_h = alloc_us(8 * M1);       unsigned short* outwT_l = alloc_us(8 * M1);
    unsigned short* saS_h  = alloc_us(M1 / 2);        unsigned short* saS_l  = alloc_us(M1 / 2);
    unsigned short* ctxS_h = alloc_us(M1);            unsigned short* ctxS_l = alloc_us(M1);
    unsigned short* catS_h = alloc_us(2 * M1);        unsigned short* catS_l = alloc_us(2 * M1);
    unsigned short* h1S_h  = alloc_us(2 * M1);        unsigned short* h1S_l  = alloc_us(2 * M1);
    unsigned short* soS_h  = alloc_us(M1);            unsigned short* soS_l  = alloc_us(M1);
    // attention split planes
    unsigned short* qhS_h  = alloc_us(M1);            unsigned short* qhS_l  = alloc_us(M1);
    unsigned short* khS_h  = alloc_us(M1);            unsigned short* khS_l  = alloc_us(M1);
    unsigned short* vtS_h  = alloc_us(M1);            unsigned short* vtS_l  = alloc_us(M1);

    // ---- one-time precompute ----
    {
        size_t n = BL * (E_ / 4);
        gather_emb<<<(unsigned)((n + 255) / 256), 256, 0, stream>>>(x, emb, emb_x);
    }
    launch_cvt(emb_x, embS_h, embS_l, BL * E_, stream);
    launch_cvtT(w_kv, E_, E_, wkvT_h, wkvT_l, stream);
    launch_gemm_split(embS_h, embS_l, wkvT_h, wkvT_l, kv, E_, nullptr, (int)BL, E_, E_, 0, stream);
    launch_cvt(kv, kvS_h, kvS_l, BL * E_, stream);
    launch_cvtT(wk, E_, E_, wkT_h, wkT_l, stream);
    launch_cvtT(wv, E_, E_, wvT_h, wvT_l, stream);
    launch_gemm_split(kvS_h, kvS_l, wkT_h, wkT_l, kh, E_, nullptr, (int)BL, E_, E_, 0, stream);
    launch_gemm_split(kvS_h, kvS_l, wvT_h, wvT_l, vh, E_, nullptr, (int)BL, E_, E_, 0, stream);
    {
        // kh holds k-linear, vh holds v-linear; rope into k_lin/v_lin then swap names
        size_t n = (size_t)B_ * L_ * NH_ * (HD_ / 2);
        rope_heads<<<(unsigned)((n + 255) / 256), 256, 0, stream>>>(kh, k_lin, L_, 1);
        rope_heads<<<(unsigned)((n + 255) / 256), 256, 0, stream>>>(vh, v_lin, L_, 0);
    }
    {
        float* tmp;
        tmp = kh; kh = k_lin; k_lin = tmp;   // kh -> head-K (B,NH,L,HD)
        tmp = vh; vh = v_lin; v_lin = tmp;   // vh -> head-V (B,NH,L,HD)
        q2  = k_lin;
        ctx = v_lin;
    }
    // split planes for attention (K once; V transposed once)
    launch_cvt(kh, khS_h, khS_l, M1, stream);
    {
        dim3 g(HD_ / 32, L_ / 32, B_ * NH_);
        cvt_split_T_bh<<<g, 256, 0, stream>>>(vh, vtS_h, vtS_l);
    }
    // fold wq: combined = w_q_sync @ wq  (SA,E)
    launch_cvt(w_q_sync, wqsS_h, wqsS_l, (size_t)SA_ * E_, stream);
    launch_cvtT(wq, E_, E_, wqT_h, wqT_l, stream);
    launch_gemm_split(wqsS_h, wqsS_l, wqT_h, wqT_l, combined, E_, nullptr, SA_, E_, E_, 0, stream);
    launch_cvtT(combined, SA_, E_, combT_h, combT_l, stream);
    // weight conversions
    launch_cvtT(wo, E_, E_, woT_h, woT_l, stream);
    launch_cvtT(ws1, E_ + W_, SYNH_, ws1T_h, ws1T_l, stream);
    launch_cvtT(ws2, SYNH_, W_, ws2T_h, ws2T_l, stream);
    launch_cvtT(out_w, SO_, V_, outwT_h, outwT_l, stream);

    init_hist0<<<(unsigned)((BQW + 255) / 256), 256, 0, stream>>>(z_init, hist);
    init_pah<<<(unsigned)((BQW * D_ + 255) / 256), 256, 0, stream>>>(pah_init, pah);
    {
        dim3 g(BQ_ / 256, SA_);
        sync_kernel<<<g, 256, 0, stream>>>(hist, 1, idx_la, idx_ra, decay_a, sync_a, SA_);
    }

    // ---- T iterations ----
    for (int t = 0; t < T_; ++t) {
        const float* z = hist + (size_t)t * BQW;

        launch_cvt(sync_a, saS_h, saS_l, BQ * SA_, stream);
        launch_gemm_split(saS_h, saS_l, combT_h, combT_l, q2, E_, nullptr, (int)BQ, E_, SA_, 0, stream);
        {
            size_t n = (size_t)B_ * Q_ * NH_ * (HD_ / 2);
            rope_heads<<<(unsigned)((n + 255) / 256), 256, 0, stream>>>(q2, qh, Q_, 1);
        }
        launch_cvt(qh, qhS_h, qhS_l, M1, stream);
        {
            dim3 g(Q_ / 64, NH_, B_);
            attn_mfma<<<g, 256, 0, stream>>>(qhS_h, qhS_l, khS_h, khS_l, vtS_h, vtS_l, ctx);
        }
        launch_cvt(ctx, ctxS_h, ctxS_l, BQ * E_, stream);
        launch_gemm_split(ctxS_h, ctxS_l, woT_h, woT_l, cat, E_ + W_, nullptr, (int)BQ, E_, E_, 0, stream);
        copy_z_cat<<<(unsigned)((BQW + 255) / 256), 256, 0, stream>>>(z, cat);

        launch_cvt(cat, catS_h, catS_l, BQ * (E_ + W_), stream);
        launch_gemm_split(catS_h, catS_l, ws1T_h, ws1T_l, h1, SYNH_, bs1, (int)BQ, SYNH_, E_ + W_, 1, stream);
        launch_cvt(h1, h1S_h, h1S_l, BQ * SYNH_, stream);
        launch_gemm_split(h1S_h, h1S_l, ws2T_h, ws2T_l, pre, W_, bs2, (int)BQ, W_, SYNH_, 0, stream);

        float* znext = hist + (size_t)(t + 1) * BQW;
        {
            dim3 g(BQ_ / 256, W_);
            nlm_kernel<<<g, 256, 0, stream>>>(pah, pre, nlm_w1, nlm_b1, nlm_w2, nlm_b2, znext);
        }

        int Tn = t + 2;
        if (t < T_ - 1) {
            dim3 g(BQ_ / 256, SA_);
            sync_kernel<<<g, 256, 0, stream>>>(hist, Tn, idx_la, idx_ra, decay_a, sync_a, SA_);
        }
        {
            dim3 g(BQ_ / 256, SO_);
            sync_kernel<<<g, 256, 0, stream>>>(hist, Tn, idx_lo, idx_ro, decay_o, sync_o, SO_);
        }

        launch_cvt(sync_o, soS_h, soS_l, BQ * SO_, stream);
        float* out_t = out + (size_t)t * BQ * V_;
        launch_gemm_split(soS_h, soS_l, outwT_h, outwT_l, out_t, V_, out_b, (int)BQ, V_, SO_, 0, stream);
    }
}

// Round 3
// 2100.693 us; speedup vs baseline: 2.5016x; 1.3820x over previous
//
#include <hip/hip_runtime.h>

#define B_ 2
#define L_ 512
#define Q_ 512
#define E_ 1024
#define W_ 1024
#define D_ 8
#define H_ 32
#define NH_ 16
#define HD_ 64
#define SA_ 512
#define SO_ 1024
#define V_ 8192
#define T_ 6
#define SYNH_ 2048

#define BQ_ 1024  // B_*Q_
#define BL_ 1024  // B_*L_

typedef __attribute__((ext_vector_type(8))) short bf16x8;   // 8 bf16 = 4 VGPRs
typedef __attribute__((ext_vector_type(4))) float f32x4;    // MFMA 16x16 accum

__device__ __forceinline__ float gelu_f(float x) {
    const float c = 0.7978845608028654f; // sqrt(2/pi)
    float x3 = x * x * x;
    return 0.5f * x * (1.0f + tanhf(c * (x + 0.044715f * x3)));
}

// ---- bf16 helpers (RNE) ----
__device__ __forceinline__ unsigned short f2bf(float x) {
    unsigned int u = __float_as_uint(x);
    u += 0x7fffu + ((u >> 16) & 1u);
    return (unsigned short)(u >> 16);
}
__device__ __forceinline__ float bf2f(unsigned short h) {
    return __uint_as_float(((unsigned int)h) << 16);
}

// ---- async global->LDS, 16B per lane (dest = wave-uniform base + lane*16) ----
__device__ __forceinline__ void gload16(const void* g, void* l) {
    __builtin_amdgcn_global_load_lds(
        (const __attribute__((address_space(1))) void*)g,
        (__attribute__((address_space(3))) void*)l, 16, 0, 0);
}

// =====================================================================
// Split-bf16 MFMA GEMM, double-buffered 2-phase pipeline.
// A: hi/lo planes (M,K) row-major, stride K. B: hi/lo planes (N,K), stride K.
// Outputs: fp32 C (nullable) and/or split planes CH/CL (nullable), stride ldc.
// TILE in {64,128}: M%TILE==0, N%TILE==0, K%32==0.
// LDS XOR-swizzle: 16B-chunk c at row r stored at c ^ ((r>>1)&3)
// (both-sides: pre-swizzled global src + swizzled ds_read; linear lds dest).
// K-step: issue next-tile gload_lds, ds_read frags, 3*FR*FR MFMA,
// vmcnt(0)+single barrier  (T3-minimum 2-phase).
// =====================================================================
template<int TILE>
__global__ __launch_bounds__(256) void gemm_split_db(
    const unsigned short* __restrict__ Ah, const unsigned short* __restrict__ Al,
    const unsigned short* __restrict__ Bh, const unsigned short* __restrict__ Bl,
    float* __restrict__ C, unsigned short* __restrict__ CHp, unsigned short* __restrict__ CLp,
    int ldc, const float* __restrict__ bias,
    int M, int N, int K, int act)
{
    constexpr int FR = TILE / 32;            // frags per wave per dim (4 or 2)
    constexpr int TS = TILE * 32;            // shorts per tile-plane
    constexpr int NP = TS / 8 / 256;         // staging passes (2 or 1)
    __shared__ unsigned short sAh[2][TS], sAl[2][TS], sBh[2][TS], sBl[2][TS];

    const int tid  = threadIdx.x;
    const int wave = tid >> 6;
    const int lane = tid & 63;
    const int r15 = lane & 15;
    const int r4  = lane >> 4;
    const int bm = blockIdx.y * TILE;
    const int bn = blockIdx.x * TILE;
    const int wm = (wave >> 1) * (TILE / 2);
    const int wn = (wave & 1) * (TILE / 2);

    f32x4 acc[FR][FR] = {};

    // per-lane swizzled source offsets; wave-uniform LDS dests
    size_t goffA[NP], goffB[NP];
    int ldst[NP];
#pragma unroll
    for (int p2 = 0; p2 < NP; ++p2) {
        int ch = p2 * 256 + tid;
        int row = ch >> 2, c = ch & 3;
        int cs = c ^ ((row >> 1) & 3);
        goffA[p2] = (size_t)(bm + row) * K + cs * 8;
        goffB[p2] = (size_t)(bn + row) * K + cs * 8;
        ldst[p2] = (p2 * 256 + wave * 64) * 8;
    }

    const int nk = K / 32;
    // prologue: stage buffer 0
#pragma unroll
    for (int p2 = 0; p2 < NP; ++p2) {
        gload16(Ah + goffA[p2], &sAh[0][ldst[p2]]);
        gload16(Al + goffA[p2], &sAl[0][ldst[p2]]);
        gload16(Bh + goffB[p2], &sBh[0][ldst[p2]]);
        gload16(Bl + goffB[p2], &sBl[0][ldst[p2]]);
    }
    asm volatile("s_waitcnt vmcnt(0)" ::: "memory");
    __syncthreads();

    for (int t = 0; t < nk; ++t) {
        const int cur = t & 1;
        if (t + 1 < nk) {
            const size_t kadd = (size_t)(t + 1) * 32;
#pragma unroll
            for (int p2 = 0; p2 < NP; ++p2) {
                gload16(Ah + goffA[p2] + kadd, &sAh[cur ^ 1][ldst[p2]]);
                gload16(Al + goffA[p2] + kadd, &sAl[cur ^ 1][ldst[p2]]);
                gload16(Bh + goffB[p2] + kadd, &sBh[cur ^ 1][ldst[p2]]);
                gload16(Bl + goffB[p2] + kadd, &sBl[cur ^ 1][ldst[p2]]);
            }
        }
        bf16x8 afh[FR], afl[FR], bfh[FR], bfl[FR];
#pragma unroll
        for (int i = 0; i < FR; ++i) {
            const int row = wm + i * 16 + r15;
            const int off = row * 32 + (r4 ^ ((row >> 1) & 3)) * 8;
            afh[i] = *(const bf16x8*)(&sAh[cur][off]);
            afl[i] = *(const bf16x8*)(&sAl[cur][off]);
        }
#pragma unroll
        for (int j = 0; j < FR; ++j) {
            const int row = wn + j * 16 + r15;
            const int off = row * 32 + (r4 ^ ((row >> 1) & 3)) * 8;
            bfh[j] = *(const bf16x8*)(&sBh[cur][off]);
            bfl[j] = *(const bf16x8*)(&sBl[cur][off]);
        }
#pragma unroll
        for (int i = 0; i < FR; ++i)
#pragma unroll
            for (int j = 0; j < FR; ++j) {
                acc[i][j] = __builtin_amdgcn_mfma_f32_16x16x32_bf16(afh[i], bfh[j], acc[i][j], 0, 0, 0);
                acc[i][j] = __builtin_amdgcn_mfma_f32_16x16x32_bf16(afh[i], bfl[j], acc[i][j], 0, 0, 0);
                acc[i][j] = __builtin_amdgcn_mfma_f32_16x16x32_bf16(afl[i], bfh[j], acc[i][j], 0, 0, 0);
            }
        asm volatile("s_waitcnt vmcnt(0)" ::: "memory");
        __syncthreads();
    }

    // epilogue: C/D layout col=lane&15, row=(lane>>4)*4+reg
    const int crow0 = bm + wm + r4 * 4;
    const int ccol0 = bn + wn + r15;
#pragma unroll
    for (int i = 0; i < FR; ++i) {
#pragma unroll
        for (int j = 0; j < FR; ++j) {
            const int col = ccol0 + j * 16;
            const float bv = bias ? bias[col] : 0.0f;
#pragma unroll
            for (int r = 0; r < 4; ++r) {
                const int row = crow0 + i * 16 + r;
                float v = acc[i][j][r] + bv;
                if (act) v = gelu_f(v);
                const size_t o = (size_t)row * ldc + col;
                if (C) C[o] = v;
                if (CHp) {
                    unsigned short hh = f2bf(v);
                    CHp[o] = hh;
                    CLp[o] = f2bf(v - bf2f(hh));
                }
            }
        }
    }
}

// =====================================================================
// MFMA flash attention (split-bf16, fp32 softmax), split-plane output.
// =====================================================================
__global__ __launch_bounds__(256) void attn_mfma(
    const unsigned short* __restrict__ qh_h, const unsigned short* __restrict__ qh_l,
    const unsigned short* __restrict__ kh_h, const unsigned short* __restrict__ kh_l,
    const unsigned short* __restrict__ vt_h, const unsigned short* __restrict__ vt_l,
    unsigned short* __restrict__ ctxH, unsigned short* __restrict__ ctxL)
{
    __shared__ unsigned short sKh[64 * 64], sKl[64 * 64];
    __shared__ unsigned short sVh[64 * 64], sVl[64 * 64];
    __shared__ unsigned short sPh[64 * 64], sPl[64 * 64];

    const int tid  = threadIdx.x;
    const int wave = tid >> 6;
    const int lane = tid & 63;
    const int r15 = lane & 15;
    const int r4  = lane >> 4;
    const int qt = blockIdx.x;
    const int h  = blockIdx.y;
    const int b  = blockIdx.z;
    const int bh = b * NH_ + h;
    const int qbase = qt * 64 + wave * 16;

    bf16x8 qa[2][2];
    {
        const unsigned short* qr_h = qh_h + ((size_t)bh * Q_ + qbase + r15) * HD_ + r4 * 8;
        const unsigned short* qr_l = qh_l + ((size_t)bh * Q_ + qbase + r15) * HD_ + r4 * 8;
        qa[0][0] = *(const bf16x8*)(qr_h);
        qa[1][0] = *(const bf16x8*)(qr_h + 32);
        qa[0][1] = *(const bf16x8*)(qr_l);
        qa[1][1] = *(const bf16x8*)(qr_l + 32);
    }

    f32x4 of[4] = {};
    float mrow[4] = {-1e30f, -1e30f, -1e30f, -1e30f};
    float lrow[4] = {};

    const int row0 = tid >> 3,        i70 = tid & 7;
    const int row1 = 32 + (tid >> 3), i71 = tid & 7;
    const int ko0 = row0 * 64 + ((i70 * 8) ^ ((row0 & 7) << 3));
    const int ko1 = row1 * 64 + ((i71 * 8) ^ ((row1 & 7) << 3));
    const size_t vo0 = (size_t)row0 * L_ + ((i70 * 8) ^ ((row0 & 7) << 3));
    const size_t vo1 = (size_t)row1 * L_ + ((i71 * 8) ^ ((row1 & 7) << 3));
    const int ld0 = wave * 512;
    const int ld1 = 2048 + wave * 512;

    const unsigned short* kb_h = kh_h + (size_t)bh * L_ * HD_;
    const unsigned short* kb_l = kh_l + (size_t)bh * L_ * HD_;
    const unsigned short* vb_h = vt_h + (size_t)bh * HD_ * L_;
    const unsigned short* vb_l = vt_l + (size_t)bh * HD_ * L_;

    for (int kt = 0; kt <= qt; ++kt) {
        gload16(kb_h + kt * 4096 + ko0, sKh + ld0);
        gload16(kb_h + kt * 4096 + ko1, sKh + ld1);
        gload16(kb_l + kt * 4096 + ko0, sKl + ld0);
        gload16(kb_l + kt * 4096 + ko1, sKl + ld1);
        gload16(vb_h + vo0 + kt * 64, sVh + ld0);
        gload16(vb_h + vo1 + kt * 64, sVh + ld1);
        gload16(vb_l + vo0 + kt * 64, sVl + ld0);
        gload16(vb_l + vo1 + kt * 64, sVl + ld1);
        asm volatile("s_waitcnt vmcnt(0)" ::: "memory");
        __syncthreads();

        f32x4 sf[4] = {};
#pragma unroll
        for (int ks = 0; ks < 2; ++ks) {
#pragma unroll
            for (int j = 0; j < 4; ++j) {
                const int kr = j * 16 + r15;
                const int off = kr * 64 + (((ks * 32 + r4 * 8)) ^ ((kr & 7) << 3));
                bf16x8 kfh = *(const bf16x8*)(sKh + off);
                bf16x8 kfl = *(const bf16x8*)(sKl + off);
                sf[j] = __builtin_amdgcn_mfma_f32_16x16x32_bf16(qa[ks][0], kfh, sf[j], 0, 0, 0);
                sf[j] = __builtin_amdgcn_mfma_f32_16x16x32_bf16(qa[ks][0], kfl, sf[j], 0, 0, 0);
                sf[j] = __builtin_amdgcn_mfma_f32_16x16x32_bf16(qa[ks][1], kfh, sf[j], 0, 0, 0);
            }
        }

        const bool diag = (kt == qt);
#pragma unroll
        for (int j = 0; j < 4; ++j)
#pragma unroll
            for (int r = 0; r < 4; ++r) {
                float s = sf[j][r] * 0.125f;
                if (diag) {
                    int kg = kt * 64 + j * 16 + r15;
                    int qg = qt * 64 + wave * 16 + r4 * 4 + r;
                    if (kg > qg) s = -1e30f;
                }
                sf[j][r] = s;
            }

        float pv[4][4];
#pragma unroll
        for (int r = 0; r < 4; ++r) {
            float mx = fmaxf(fmaxf(sf[0][r], sf[1][r]), fmaxf(sf[2][r], sf[3][r]));
#pragma unroll
            for (int d = 1; d < 16; d <<= 1) mx = fmaxf(mx, __shfl_xor(mx, d, 64));
            float mnew = fmaxf(mrow[r], mx);
            float corr = expf(mrow[r] - mnew);
            float rs = 0.0f;
#pragma unroll
            for (int j = 0; j < 4; ++j) {
                float pp = expf(sf[j][r] - mnew);
                pv[j][r] = pp;
                rs += pp;
            }
#pragma unroll
            for (int d = 1; d < 16; d <<= 1) rs += __shfl_xor(rs, d, 64);
            lrow[r] = lrow[r] * corr + rs;
            mrow[r] = mnew;
#pragma unroll
            for (int j = 0; j < 4; ++j) of[j][r] *= corr;
        }

#pragma unroll
        for (int j = 0; j < 4; ++j)
#pragma unroll
            for (int r = 0; r < 4; ++r) {
                const int prow = wave * 16 + r4 * 4 + r;
                const int pcol = j * 16 + r15;
                const int off = prow * 64 + (pcol ^ ((prow & 7) << 3));
                unsigned short ph = f2bf(pv[j][r]);
                sPh[off] = ph;
                sPl[off] = f2bf(pv[j][r] - bf2f(ph));
            }
        __syncthreads();

#pragma unroll
        for (int ks = 0; ks < 2; ++ks) {
            const int arow = wave * 16 + r15;
            const int aoff = arow * 64 + (((ks * 32 + r4 * 8)) ^ ((arow & 7) << 3));
            bf16x8 pah = *(const bf16x8*)(sPh + aoff);
            bf16x8 pal = *(const bf16x8*)(sPl + aoff);
#pragma unroll
            for (int j = 0; j < 4; ++j) {
                const int vrow = j * 16 + r15;
                const int voff = vrow * 64 + (((ks * 32 + r4 * 8)) ^ ((vrow & 7) << 3));
                bf16x8 vfh = *(const bf16x8*)(sVh + voff);
                bf16x8 vfl = *(const bf16x8*)(sVl + voff);
                of[j] = __builtin_amdgcn_mfma_f32_16x16x32_bf16(pah, vfh, of[j], 0, 0, 0);
                of[j] = __builtin_amdgcn_mfma_f32_16x16x32_bf16(pah, vfl, of[j], 0, 0, 0);
                of[j] = __builtin_amdgcn_mfma_f32_16x16x32_bf16(pal, vfh, of[j], 0, 0, 0);
            }
        }
        __syncthreads();
    }

    float linv[4];
#pragma unroll
    for (int r = 0; r < 4; ++r) linv[r] = 1.0f / lrow[r];
#pragma unroll
    for (int j = 0; j < 4; ++j)
#pragma unroll
        for (int r = 0; r < 4; ++r) {
            const int qg = qt * 64 + wave * 16 + r4 * 4 + r;
            const int dc = h * HD_ + j * 16 + r15;
            const size_t o = ((size_t)b * Q_ + qg) * E_ + dc;
            float v = of[j][r] * linv[r];
            unsigned short hh = f2bf(v);
            ctxH[o] = hh;
            ctxL[o] = f2bf(v - bf2f(hh));
        }
}

// ---------------- fp32 -> split bf16 (row-major) ----------------
__global__ void cvt_split(const float* __restrict__ X,
                          unsigned short* __restrict__ H, unsigned short* __restrict__ L,
                          size_t n4)
{
    size_t i = (size_t)blockIdx.x * 256 + threadIdx.x;
    if (i >= n4) return;
    float4 v = ((const float4*)X)[i];
    ushort4 h, l;
    h.x = f2bf(v.x); l.x = f2bf(v.x - bf2f(h.x));
    h.y = f2bf(v.y); l.y = f2bf(v.y - bf2f(h.y));
    h.z = f2bf(v.z); l.z = f2bf(v.z - bf2f(h.z));
    h.w = f2bf(v.w); l.w = f2bf(v.w - bf2f(h.w));
    ((ushort4*)H)[i] = h;
    ((ushort4*)L)[i] = l;
}

// ---------------- fp32 (R,C) -> split bf16 transposed (C,R) ----------------
__global__ __launch_bounds__(256) void cvt_split_T(
    const float* __restrict__ X, int R, int Cc,
    unsigned short* __restrict__ H, unsigned short* __restrict__ L)
{
    __shared__ float tile[32][33];
    const int rb = blockIdx.y * 32, cb = blockIdx.x * 32;
    const int tx = threadIdx.x & 31, ty = threadIdx.x >> 5;
#pragma unroll
    for (int r = 0; r < 32; r += 8)
        tile[ty + r][tx] = X[(size_t)(rb + ty + r) * Cc + cb + tx];
    __syncthreads();
#pragma unroll
    for (int r = 0; r < 32; r += 8) {
        float v = tile[tx][ty + r];
        unsigned short h = f2bf(v);
        unsigned short l = f2bf(v - bf2f(h));
        size_t o = (size_t)(cb + ty + r) * R + rb + tx;
        H[o] = h;
        L[o] = l;
    }
}

// ---- V transpose+split: v_lin (B,L,E) -> vtS (B*NH, HD, L) ----
__global__ __launch_bounds__(256) void vtrans_split(
    const float* __restrict__ v_lin,
    unsigned short* __restrict__ H, unsigned short* __restrict__ L)
{
    __shared__ float tile[32][33];
    const int bh = blockIdx.z;
    const int b = bh >> 4, h = bh & 15;
    const int rb = blockIdx.y * 32;   // L rows
    const int cb = blockIdx.x * 32;   // HD cols
    const int tx = threadIdx.x & 31, ty = threadIdx.x >> 5;
#pragma unroll
    for (int r = 0; r < 32; r += 8)
        tile[ty + r][tx] = v_lin[((size_t)b * L_ + rb + ty + r) * E_ + h * HD_ + cb + tx];
    __syncthreads();
#pragma unroll
    for (int r = 0; r < 32; r += 8) {
        float v = tile[tx][ty + r];
        unsigned short hh = f2bf(v);
        unsigned short ll = f2bf(v - bf2f(hh));
        size_t o = (size_t)bh * HD_ * L_ + (size_t)(cb + ty + r) * L_ + rb + tx;
        H[o] = hh;
        L[o] = ll;
    }
}

// ---------------- embedding gather + split ----------------
__global__ void gather_emb_split(const int* __restrict__ x, const float* __restrict__ emb,
                                 unsigned short* __restrict__ H, unsigned short* __restrict__ L) {
    size_t i = (size_t)blockIdx.x * 256 + threadIdx.x;
    const int e4n = E_ / 4;
    size_t row = i / e4n;
    int e4 = (int)(i % e4n);
    float4 v = *(((const float4*)(emb + (size_t)x[row] * E_)) + e4);
    ushort4 h, l;
    h.x = f2bf(v.x); l.x = f2bf(v.x - bf2f(h.x));
    h.y = f2bf(v.y); l.y = f2bf(v.y - bf2f(h.y));
    h.z = f2bf(v.z); l.z = f2bf(v.z - bf2f(h.z));
    h.w = f2bf(v.w); l.w = f2bf(v.w - bf2f(h.w));
    ((ushort4*)H)[i] = h;
    ((ushort4*)L)[i] = l;
}

// ---------------- heads reshape + RoPE -> split planes ----------------
__global__ void rope_heads_split(const float* __restrict__ lin,
                                 unsigned short* __restrict__ OH, unsigned short* __restrict__ OL,
                                 int S, int applyRope) {
    const int half = HD_ / 2;  // 32
    size_t idx = (size_t)blockIdx.x * 256 + threadIdx.x;
    size_t total = (size_t)B_ * S * NH_ * half;
    if (idx >= total) return;
    int d2 = (int)(idx % half);
    int h = (int)((idx / half) % NH_);
    int s = (int)((idx / ((size_t)half * NH_)) % S);
    int b = (int)(idx / ((size_t)half * NH_ * S));
    const float* src = lin + ((size_t)b * S + s) * E_ + h * HD_;
    float x1 = src[d2], x2 = src[d2 + half];
    float o1, o2;
    if (applyRope) {
        float invf = powf(10000.0f, -(float)d2 / (float)half);
        float ang = (float)s * invf;
        float c = cosf(ang), sn = sinf(ang);
        o1 = x1 * c - x2 * sn;
        o2 = x2 * c + x1 * sn;
    } else {
        o1 = x1; o2 = x2;
    }
    size_t dbase = (((size_t)b * NH_ + h) * S + s) * HD_;
    unsigned short h1s = f2bf(o1);
    unsigned short h2s = f2bf(o2);
    OH[dbase + d2] = h1s;
    OL[dbase + d2] = f2bf(o1 - bf2f(h1s));
    OH[dbase + d2 + half] = h2s;
    OL[dbase + d2 + half] = f2bf(o2 - bf2f(h2s));
}

// ---------------- state init ----------------
__global__ void init_hist0(const float* __restrict__ z_init, float* __restrict__ hist0) {
    size_t i = (size_t)blockIdx.x * 256 + threadIdx.x;  // W*BQ
    if (i >= (size_t)W_ * BQ_) return;
    hist0[i] = z_init[i / BQ_];
}

__global__ void init_pah(const float* __restrict__ pah_init, float* __restrict__ pah) {
    size_t i = (size_t)blockIdx.x * 256 + threadIdx.x;  // W*BQ*D
    if (i >= (size_t)W_ * BQ_ * D_) return;
    int d = (int)(i % D_);
    int w = (int)(i / ((size_t)BQ_ * D_));
    pah[i] = pah_init[(size_t)w * D_ + d];
}

// ---------------- sync computation -> split planes ----------------
__global__ __launch_bounds__(256) void sync_kernel(
    const float* __restrict__ hist, int Tn,
    const int* __restrict__ idx_l, const int* __restrict__ idx_r,
    const float* __restrict__ decay,
    unsigned short* __restrict__ outH, unsigned short* __restrict__ outL, int S) {
    const int s = blockIdx.y;
    const int bq = blockIdx.x * 256 + threadIdx.x;
    const int wl = idx_l[s], wr = idx_r[s];
    const float dc = decay[s];
    float num = 0.0f, den = 0.0f;
    for (int t = 0; t < Tn; ++t) {
        float wgt = expf(-(float)(Tn - 1 - t) * dc);
        const float* hp = hist + (size_t)t * W_ * BQ_;
        num = fmaf(wgt * hp[(size_t)wl * BQ_ + bq], hp[(size_t)wr * BQ_ + bq], num);
        den += wgt;
    }
    float v = num * rsqrtf(den);
    unsigned short hh = f2bf(v);
    outH[(size_t)bq * S + s] = hh;
    outL[(size_t)bq * S + s] = f2bf(v - bf2f(hh));
}

// ---------------- z -> split planes into cat[:, E:] ----------------
__global__ void copy_z_cat_split(const float* __restrict__ z,
                                 unsigned short* __restrict__ catH,
                                 unsigned short* __restrict__ catL) {
    size_t i = (size_t)blockIdx.x * 256 + threadIdx.x;  // BQ*W
    if (i >= (size_t)BQ_ * W_) return;
    size_t bq = i / W_;
    int w = (int)(i % W_);
    float v = z[(size_t)w * BQ_ + bq];
    unsigned short hh = f2bf(v);
    size_t o = bq * (E_ + W_) + E_ + w;
    catH[o] = hh;
    catL[o] = f2bf(v - bf2f(hh));
}

// ---------------- pah shift + NLM ----------------
__global__ __launch_bounds__(256) void nlm_kernel(
    float* __restrict__ pah,
    const float* __restrict__ pre,
    const float* __restrict__ w1,
    const float* __restrict__ b1,
    const float* __restrict__ w2,
    const float* __restrict__ b2,
    float* __restrict__ zout)
{
    const int w = blockIdx.y;
    const int bq = blockIdx.x * 256 + threadIdx.x;
    const int tid = threadIdx.x;

    __shared__ float w1s[D_ * H_];
    __shared__ float b1s[H_];
    __shared__ float w2s[H_];
    w1s[tid] = w1[(size_t)w * D_ * H_ + tid];
    if (tid < H_) {
        b1s[tid] = b1[(size_t)w * H_ + tid];
        w2s[tid] = w2[(size_t)w * H_ + tid];
    }
    __syncthreads();

    float* pp = pah + ((size_t)w * BQ_ + bq) * D_;
    float4 lo = *(float4*)pp;
    float4 hi = *(float4*)(pp + 4);
    float p[D_];
    p[0] = lo.y; p[1] = lo.z; p[2] = lo.w;
    p[3] = hi.x; p[4] = hi.y; p[5] = hi.z; p[6] = hi.w;
    p[7] = pre[(size_t)bq * W_ + w];
    *(float4*)pp = make_float4(p[0], p[1], p[2], p[3]);
    *(float4*)(pp + 4) = make_float4(p[4], p[5], p[6], p[7]);

    float zacc = b2[w];
#pragma unroll
    for (int j = 0; j < H_; ++j) {
        float a = b1s[j];
#pragma unroll
        for (int d = 0; d < D_; ++d) a = fmaf(p[d], w1s[d * H_ + j], a);
        zacc = fmaf(gelu_f(a), w2s[j], zacc);
    }
    zout[(size_t)w * BQ_ + bq] = zacc;
}

// ---------------- host orchestration ----------------
static inline void gemm64(const unsigned short* Ah, const unsigned short* Al,
                          const unsigned short* Bh, const unsigned short* Bl,
                          float* C, unsigned short* CH, unsigned short* CL, int ldc,
                          const float* bias, int M, int N, int K, int act, hipStream_t s) {
    dim3 g(N / 64, M / 64);
    gemm_split_db<64><<<g, 256, 0, s>>>(Ah, Al, Bh, Bl, C, CH, CL, ldc, bias, M, N, K, act);
}
static inline void gemm128(const unsigned short* Ah, const unsigned short* Al,
                           const unsigned short* Bh, const unsigned short* Bl,
                           float* C, unsigned short* CH, unsigned short* CL, int ldc,
                           const float* bias, int M, int N, int K, int act, hipStream_t s) {
    dim3 g(N / 128, M / 128);
    gemm_split_db<128><<<g, 256, 0, s>>>(Ah, Al, Bh, Bl, C, CH, CL, ldc, bias, M, N, K, act);
}

static inline void launch_cvt(const float* X, unsigned short* H, unsigned short* L,
                              size_t n, hipStream_t s) {
    size_t n4 = n / 4;
    cvt_split<<<(unsigned)((n4 + 255) / 256), 256, 0, s>>>(X, H, L, n4);
}

static inline void launch_cvtT(const float* X, int R, int C,
                               unsigned short* H, unsigned short* L, hipStream_t s) {
    dim3 g(C / 32, R / 32);
    cvt_split_T<<<g, 256, 0, s>>>(X, R, C, H, L);
}

extern "C" void kernel_launch(void* const* d_in, const int* in_sizes, int n_in,
                              void* d_out, int out_size, void* d_ws, size_t ws_size,
                              hipStream_t stream) {
    const int*   x        = (const int*)d_in[0];
    const float* emb      = (const float*)d_in[2];
    const float* w_kv     = (const float*)d_in[3];
    const float* w_q_sync = (const float*)d_in[4];
    const float* wq       = (const float*)d_in[5];
    const float* wk       = (const float*)d_in[6];
    const float* wv       = (const float*)d_in[7];
    const float* wo       = (const float*)d_in[8];
    const float* ws1      = (const float*)d_in[9];
    const float* bs1      = (const float*)d_in[10];
    const float* ws2      = (const float*)d_in[11];
    const float* bs2      = (const float*)d_in[12];
    const float* nlm_w1   = (const float*)d_in[13];
    const float* nlm_b1   = (const float*)d_in[14];
    const float* nlm_w2   = (const float*)d_in[15];
    const float* nlm_b2   = (const float*)d_in[16];
    const float* out_w    = (const float*)d_in[17];
    const float* out_b    = (const float*)d_in[18];
    const float* z_init   = (const float*)d_in[19];
    const float* pah_init = (const float*)d_in[20];
    const float* decay_a  = (const float*)d_in[21];
    const float* decay_o  = (const float*)d_in[22];
    const int*   idx_la   = (const int*)d_in[23];
    const int*   idx_ra   = (const int*)d_in[24];
    const int*   idx_lo   = (const int*)d_in[25];
    const int*   idx_ro   = (const int*)d_in[26];

    float* out = (float*)d_out;

    const size_t BQ  = BQ_;
    const size_t BL  = BL_;
    const size_t BQW = BQ * W_;
    const size_t M1  = (size_t)1024 * 1024;

    // ---- workspace carve ----
    float* p = (float*)d_ws;
    auto alloc = [&](size_t n) { float* r = p; p += n; return r; };
    auto alloc_us = [&](size_t n) { unsigned short* r = (unsigned short*)p; p += n / 2; return r; };

    float* k_lin  = alloc(M1);          // fp32 scratch; reused as q2 after precompute
    float* v_lin  = alloc(M1);
    float* pre    = alloc(M1);
    float* hist   = alloc((size_t)(T_ + 1) * BQW);
    float* pah    = alloc(BQW * D_);
    float* combined = alloc((size_t)SA_ * E_);  // w_q_sync @ wq, fp32

    float* q2 = k_lin;

    // split bf16 planes (ushort)
    unsigned short* embS_h = alloc_us(M1);            unsigned short* embS_l = alloc_us(M1);
    unsigned short* wkvT_h = alloc_us(M1);            unsigned short* wkvT_l = alloc_us(M1);
    unsigned short* kvS_h  = alloc_us(M1);            unsigned short* kvS_l  = alloc_us(M1);
    unsigned short* wkT_h  = alloc_us(M1);            unsigned short* wkT_l  = alloc_us(M1);
    unsigned short* wvT_h  = alloc_us(M1);            unsigned short* wvT_l  = alloc_us(M1);
    unsigned short* wqsS_h = alloc_us(M1 / 2);        unsigned short* wqsS_l = alloc_us(M1 / 2);
    unsigned short* wqT_h  = alloc_us(M1);            unsigned short* wqT_l  = alloc_us(M1);
    unsigned short* combT_h = alloc_us(M1 / 2);       unsigned short* combT_l = alloc_us(M1 / 2);
    unsigned short* woT_h  = alloc_us(M1);            unsigned short* woT_l  = alloc_us(M1);
    unsigned short* ws1T_h = alloc_us(4 * M1);        unsigned short* ws1T_l = alloc_us(4 * M1);
    unsigned short* ws2T_h = alloc_us(2 * M1);        unsigned short* ws2T_l = alloc_us(2 * M1);
    unsigned short* outwT_h = alloc_us(8 * M1);       unsigned short* outwT_l = alloc_us(8 * M1);
    unsigned short* saS_h  = alloc_us(M1 / 2);        unsigned short* saS_l  = alloc_us(M1 / 2);
    unsigned short* ctxS_h = alloc_us(M1);            unsigned short* ctxS_l = alloc_us(M1);
    unsigned short* catS_h = alloc_us(2 * M1);        unsigned short* catS_l = alloc_us(2 * M1);
    unsigned short* h1S_h  = alloc_us(2 * M1);        unsigned short* h1S_l  = alloc_us(2 * M1);
    unsigned short* soS_h  = alloc_us(M1);            unsigned short* soS_l  = alloc_us(M1);
    unsigned short* qhS_h  = alloc_us(M1);            unsigned short* qhS_l  = alloc_us(M1);
    unsigned short* khS_h  = alloc_us(M1);            unsigned short* khS_l  = alloc_us(M1);
    unsigned short* vtS_h  = alloc_us(M1);            unsigned short* vtS_l  = alloc_us(M1);

    // ---- one-time precompute ----
    {
        size_t n = BL * (E_ / 4);
        gather_emb_split<<<(unsigned)((n + 255) / 256), 256, 0, stream>>>(x, emb, embS_h, embS_l);
    }
    launch_cvtT(w_kv, E_, E_, wkvT_h, wkvT_l, stream);
    gemm64(embS_h, embS_l, wkvT_h, wkvT_l, nullptr, kvS_h, kvS_l, E_, nullptr, (int)BL, E_, E_, 0, stream);
    launch_cvtT(wk, E_, E_, wkT_h, wkT_l, stream);
    launch_cvtT(wv, E_, E_, wvT_h, wvT_l, stream);
    gemm64(kvS_h, kvS_l, wkT_h, wkT_l, k_lin, nullptr, nullptr, E_, nullptr, (int)BL, E_, E_, 0, stream);
    gemm64(kvS_h, kvS_l, wvT_h, wvT_l, v_lin, nullptr, nullptr, E_, nullptr, (int)BL, E_, E_, 0, stream);
    {
        size_t n = (size_t)B_ * L_ * NH_ * (HD_ / 2);
        rope_heads_split<<<(unsigned)((n + 255) / 256), 256, 0, stream>>>(k_lin, khS_h, khS_l, L_, 1);
    }
    {
        dim3 g(HD_ / 32, L_ / 32, B_ * NH_);
        vtrans_split<<<g, 256, 0, stream>>>(v_lin, vtS_h, vtS_l);
    }
    // fold wq: combined = w_q_sync @ wq  (SA,E)
    launch_cvt(w_q_sync, wqsS_h, wqsS_l, (size_t)SA_ * E_, stream);
    launch_cvtT(wq, E_, E_, wqT_h, wqT_l, stream);
    gemm64(wqsS_h, wqsS_l, wqT_h, wqT_l, combined, nullptr, nullptr, E_, nullptr, SA_, E_, E_, 0, stream);
    launch_cvtT(combined, SA_, E_, combT_h, combT_l, stream);
    // weight conversions
    launch_cvtT(wo, E_, E_, woT_h, woT_l, stream);
    launch_cvtT(ws1, E_ + W_, SYNH_, ws1T_h, ws1T_l, stream);
    launch_cvtT(ws2, SYNH_, W_, ws2T_h, ws2T_l, stream);
    launch_cvtT(out_w, SO_, V_, outwT_h, outwT_l, stream);

    init_hist0<<<(unsigned)((BQW + 255) / 256), 256, 0, stream>>>(z_init, hist);
    init_pah<<<(unsigned)((BQW * D_ + 255) / 256), 256, 0, stream>>>(pah_init, pah);
    {
        dim3 g(BQ_ / 256, SA_);
        sync_kernel<<<g, 256, 0, stream>>>(hist, 1, idx_la, idx_ra, decay_a, saS_h, saS_l, SA_);
    }

    // ---- T iterations ----
    for (int t = 0; t < T_; ++t) {
        const float* z = hist + (size_t)t * BQW;

        gemm64(saS_h, saS_l, combT_h, combT_l, q2, nullptr, nullptr, E_, nullptr, (int)BQ, E_, SA_, 0, stream);
        {
            size_t n = (size_t)B_ * Q_ * NH_ * (HD_ / 2);
            rope_heads_split<<<(unsigned)((n + 255) / 256), 256, 0, stream>>>(q2, qhS_h, qhS_l, Q_, 1);
        }
        {
            dim3 g(Q_ / 64, NH_, B_);
            attn_mfma<<<g, 256, 0, stream>>>(qhS_h, qhS_l, khS_h, khS_l, vtS_h, vtS_l, ctxS_h, ctxS_l);
        }
        gemm64(ctxS_h, ctxS_l, woT_h, woT_l, nullptr, catS_h, catS_l, E_ + W_, nullptr, (int)BQ, E_, E_, 0, stream);
        copy_z_cat_split<<<(unsigned)((BQW + 255) / 256), 256, 0, stream>>>(z, catS_h, catS_l);

        gemm64(catS_h, catS_l, ws1T_h, ws1T_l, nullptr, h1S_h, h1S_l, SYNH_, bs1, (int)BQ, SYNH_, E_ + W_, 1, stream);
        gemm64(h1S_h, h1S_l, ws2T_h, ws2T_l, pre, nullptr, nullptr, W_, bs2, (int)BQ, W_, SYNH_, 0, stream);

        float* znext = hist + (size_t)(t + 1) * BQW;
        {
            dim3 g(BQ_ / 256, W_);
            nlm_kernel<<<g, 256, 0, stream>>>(pah, pre, nlm_w1, nlm_b1, nlm_w2, nlm_b2, znext);
        }

        int Tn = t + 2;
        if (t < T_ - 1) {
            dim3 g(BQ_ / 256, SA_);
            sync_kernel<<<g, 256, 0, stream>>>(hist, Tn, idx_la, idx_ra, decay_a, saS_h, saS_l, SA_);
        }
        {
            dim3 g(BQ_ / 256, SO_);
            sync_kernel<<<g, 256, 0, stream>>>(hist, Tn, idx_lo, idx_ro, decay_o, soS_h, soS_l, SO_);
        }

        float* out_t = out + (size_t)t * BQ * V_;
        gemm128(soS_h, soS_l, outwT_h, outwT_l, out_t, nullptr, nullptr, V_, out_b, (int)BQ, V_, SO_, 0, stream);
    }
}